// Round 5
// baseline (31620.709 us; speedup 1.0000x reference)
//
#include <hip/hip_runtime.h>
#include <hip/hip_bf16.h>
#include <hip/hip_fp16.h>

#define B_ 4096
#define T_ 24
#define F_ 12
#define H_ 512
#define GH_ 2048   // 4*H
#define ZW_ 6400   // F*H + 256

// XOR swizzle: col bits 3..6 ^ row bits 0..3 (16B-fragment granularity,
// bijective within each 512-short row).
#define SWZ(row, elem) ((elem) ^ (((row) & 15) << 3))

typedef __attribute__((ext_vector_type(8))) short short8;
typedef __attribute__((ext_vector_type(4))) float f32x4;

__device__ __forceinline__ short f2bf(float f) {
    union { float f; unsigned int u; } v; v.f = f;
    unsigned int u = v.u;
    unsigned int r = (u + 0x7FFFu + ((u >> 16) & 1u)) >> 16;
    return (short)r;
}
__device__ __forceinline__ float bf2f(short b) {
    union { unsigned int u; float f; } v; v.u = ((unsigned int)(unsigned short)b) << 16;
    return v.f;
}
__device__ __forceinline__ float fastrcp(float x) { return __builtin_amdgcn_rcpf(x); }
__device__ __forceinline__ float sigm(float x) { return fastrcp(1.f + __expf(-x)); }
__device__ __forceinline__ float tanh_(float x) { return 1.f - 2.f * fastrcp(__expf(2.f * x) + 1.f); }

// ---------------------------------------------------------------- convert
// Whh packed to MFMA B-fragment order:
//   Wpk[(((f*32 + jb)*16 + kk)*4 + g)*512 + l*8 + e]
//     = bf16( Whh[f][g*512 + jb*16 + (l&15)][kk*32 + (l>>4)*8 + e] )
// Wx: x-part B-fragments (wx0, wx1, bias_hi, bias_lo, wx0, 0,0,0) on lq==0:
//   Wx[((f*32 + jb)*4 + g)*512 + l*8 + e]
__global__ void k_convert(const float* Whh, const float* dW1, const float* dW2,
                          const float* bih, const float* bhh, const float* Wih,
                          const float* sW1, const float* sW2, const float* sW3,
                          short* Wpk, short* Wx, short* odW1, short* odW2,
                          float* sW1T, float* sW2T, float* sW3T) {
    const int N2 = 1024 * ZW_;             // 6,553,600
    const int N3 = 1024 * 1024;
    const int N4 = F_ * 32 * 16 * 4 * 64;  // Wpk fragments of 8
    const int N5 = F_ * 32 * 4 * 64;       // Wx fragments of 8
    int idx = blockIdx.x * blockDim.x + threadIdx.x;
    int stride = gridDim.x * blockDim.x;
    for (int i = idx; i < N4; i += stride) {
        int l  = i & 63;
        int g  = (i >> 6) & 3;
        int kk = (i >> 8) & 15;
        int jb = (i >> 12) & 31;
        int f  = i >> 17;
        int row = g * 512 + jb * 16 + (l & 15);
        int col = kk * 32 + (l >> 4) * 8;
        const float* src = Whh + ((size_t)f * GH_ + row) * H_ + col;
        short tmp[8];
        #pragma unroll
        for (int e = 0; e < 8; e++) tmp[e] = f2bf(src[e]);
        *(short8*)(Wpk + (size_t)i * 8) = *(short8*)tmp;
    }
    for (int i = idx; i < N5; i += stride) {
        int l  = i & 63;
        int g  = (i >> 6) & 3;
        int jb = (i >> 8) & 31;
        int f  = i >> 13;
        short tmp[8] = {0, 0, 0, 0, 0, 0, 0, 0};
        if ((l >> 4) == 0) {
            int col = g * 512 + jb * 16 + (l & 15);
            float w0 = Wih[((size_t)f * GH_ + col) * 2];
            float w1 = Wih[((size_t)f * GH_ + col) * 2 + 1];
            float bs = bih[f * GH_ + col] + bhh[f * GH_ + col];
            short bh = f2bf(bs);
            short bl = f2bf(bs - bf2f(bh));
            short w0b = f2bf(w0);
            tmp[0] = w0b; tmp[1] = f2bf(w1); tmp[2] = bh; tmp[3] = bl; tmp[4] = w0b;
        }
        *(short8*)(Wx + (size_t)i * 8) = *(short8*)tmp;
    }
    for (int i = idx; i < N2; i += stride) odW1[i] = f2bf(dW1[i]);
    for (int i = idx; i < N3; i += stride) odW2[i] = f2bf(dW2[i]);
    for (int i = idx; i < 64 * 256; i += stride) {      // sW1T[i][t] = sW1[t][i]
        int r = i >> 8, t = i & 255;
        sW1T[i] = sW1[t * 64 + r];
    }
    for (int i = idx; i < 256 * 256; i += stride) {
        int r = i >> 8, t = i & 255;
        sW2T[i] = sW2[t * 256 + r];
        sW3T[i] = sW3[t * 256 + r];
    }
}

// ---------------------------------------------------------------- LSTM sub-step
// One j-subtile (16 cols) for one wave: x-MFMA init (bias+Wih*x fused) then
// 16 K-steps over h. c lives in LDS (_Float16, thread-private cells);
// new h is stashed in packed registers (written back after the barrier).
template<int S>
__device__ __forceinline__ void lstm_step_sub(
    const short* hread, _Float16* cbuf_t,
    const short* Wb, const short* WxS,
    const short8 (&ax)[4], unsigned (&hn2)[4][8],
    int l, int l15, int lq)
{
    const short* Ws = Wb + ((size_t)S << 15) + l * 8;
    short8 bx[4];
    #pragma unroll
    for (int g = 0; g < 4; g++)
        bx[g] = *(const short8*)(WxS + S * 2048 + g * 512);
    const f32x4 zero = {0.f, 0.f, 0.f, 0.f};
    f32x4 acc[4][4];
    #pragma unroll
    for (int g = 0; g < 4; g++)
        #pragma unroll
        for (int r = 0; r < 4; r++)
            acc[g][r] = __builtin_amdgcn_mfma_f32_16x16x32_bf16(ax[r], bx[g], zero, 0, 0, 0);
    #pragma unroll
    for (int kk = 0; kk < 16; kk++) {
        int k = kk * 32 + lq * 8;
        short8 a[4], bfr[4];
        #pragma unroll
        for (int r = 0; r < 4; r++) {
            int row = r * 16 + l15;
            int elem = SWZ(row, row * 512 + k);
            a[r] = *(const short8*)&hread[elem];
        }
        #pragma unroll
        for (int g = 0; g < 4; g++)
            bfr[g] = *(const short8*)(Ws + (kk * 4 + g) * 512);
        #pragma unroll
        for (int g = 0; g < 4; g++)
            #pragma unroll
            for (int r = 0; r < 4; r++)
                acc[g][r] = __builtin_amdgcn_mfma_f32_16x16x32_bf16(a[r], bfr[g], acc[g][r], 0, 0, 0);
    }
    // cell update (c in LDS f16, thread-private); stash h-new packed in regs
    #pragma unroll
    for (int r = 0; r < 4; r++) {
        #pragma unroll
        for (int pi = 0; pi < 2; pi++) {
            unsigned pack = 0;
            #pragma unroll
            for (int q = 0; q < 2; q++) {
                int p = pi * 2 + q;
                float iv = acc[0][r][p], fv = acc[1][r][p];
                float gv = acc[2][r][p], ov = acc[3][r][p];
                float cv = (float)cbuf_t[(S * 16 + r * 4 + p) * 512];
                float cn = sigm(fv) * cv + sigm(iv) * tanh_(gv);
                cbuf_t[(S * 16 + r * 4 + p) * 512] = (_Float16)cn;
                float hn = sigm(ov) * tanh_(cn);
                pack |= ((unsigned)(unsigned short)f2bf(hn)) << (16 * q);
            }
            hn2[S][r * 2 + pi] = pack;
        }
    }
}

// grid 768 (12 features x 64 batch-tiles of 64 rows), 512 threads (8 waves).
// h single-buffered bf16 in LDS (swizzled); c in LDS f16 (spill-proof by
// construction -- rounds 1-4 showed the allocator pins VGPRs at 128 and
// spills any register-resident c to scratch: 2.2-3.8 GB HBM writes/launch).
// amdgpu_waves_per_eu(2,2): direct backend knob; 2 waves/EU -> 256-reg cap.
__global__ __launch_bounds__(512)
__attribute__((amdgpu_waves_per_eu(2, 2)))
void k_lstm(const short* __restrict__ Wpk,   // packed, see k_convert
            const short* __restrict__ Wx,    // x-part fragments
            const float* __restrict__ tfeat, // [B][T][F]
            const float* __restrict__ tmask,
            const float* __restrict__ h0,    // [F][B][H]
            const float* __restrict__ c0,
            short* __restrict__ Z)           // [B][6400] bf16
{
    __shared__ __align__(16) short hbuf[64 * 512];       // 64 KB
    __shared__ _Float16 cbuf[64 * 512];                  // 64 KB, [idx][tid]
    __shared__ float xv[2][64], xm[2][64];

    int bid = blockIdx.x;
    int wg = (bid & 7) * 96 + (bid >> 3);    // XCD swizzle (768 = 8*96, bijective)
    int f = wg >> 6;
    int b0 = (wg & 63) * 64;
    int tid = threadIdx.x;
    int w = tid >> 6;
    int l = tid & 63;
    int l15 = l & 15, lq = l >> 4;

    // stage h0 -> hbuf (bf16, swizzled)
    {
        int row = tid >> 3, cg = (tid & 7) * 64;
        const float* src = h0 + ((size_t)f * B_ + b0 + row) * H_ + cg;
        #pragma unroll
        for (int i = 0; i < 64; i += 8) {
            short tmp[8];
            #pragma unroll
            for (int j = 0; j < 8; j++) tmp[j] = f2bf(src[i + j]);
            int elem = SWZ(row, row * 512 + cg + i);
            *(short8*)&hbuf[elem] = *(short8*)tmp;
        }
    }
    if (tid < 64)        xv[0][tid]      = tfeat[(size_t)(b0 + tid) * (T_ * F_) + f];
    else if (tid < 128)  xm[0][tid - 64] = tmask[(size_t)(b0 + tid - 64) * (T_ * F_) + f];

    // c0 -> cbuf (f16), idx = s*16 + r*4 + p, thread-private column tid
    #pragma unroll
    for (int s = 0; s < 4; s++) {
        int j = w * 64 + s * 16 + l15;
        #pragma unroll
        for (int r = 0; r < 4; r++) {
            const float* cp = c0 + ((size_t)f * B_ + b0 + r * 16 + lq * 4) * H_ + j;
            #pragma unroll
            for (int p = 0; p < 4; p++)
                cbuf[(s * 16 + r * 4 + p) * 512 + tid] = (_Float16)cp[(size_t)p * H_];
        }
    }
    __syncthreads();

    const short* Wb  = Wpk + (((size_t)f * 32 + w * 4) << 15);
    const short* WxS = Wx + ((size_t)(f * 32 + w * 4) * 4) * 512 + l * 8;
    _Float16* cbt = cbuf + tid;

    #pragma unroll 1
    for (int t = 0; t < T_; t++) {
        int rb = t & 1, wb = rb ^ 1;
        // prefetch x(t+1) into the other buffer (ordered by end-of-step barrier)
        if (t < T_ - 1) {
            if (tid < 64)       xv[wb][tid]      = tfeat[(size_t)(b0 + tid) * (T_ * F_) + (t + 1) * F_ + f];
            else if (tid < 128) xm[wb][tid - 64] = tmask[(size_t)(b0 + tid - 64) * (T_ * F_) + (t + 1) * F_ + f];
        }
        // build x A-fragments: rows r*16+l15, k-slots {xv_hi, xm, 1, 1, xv_lo}
        short8 ax[4];
        #pragma unroll
        for (int r = 0; r < 4; r++) {
            int row = r * 16 + l15;
            float xvf = xv[rb][row];
            float xmf = xm[rb][row];
            short hi = f2bf(xvf);
            short lo = f2bf(xvf - bf2f(hi));
            short8 v = {0, 0, 0, 0, 0, 0, 0, 0};
            if (lq == 0) {
                v[0] = hi; v[1] = f2bf(xmf);
                v[2] = (short)0x3F80; v[3] = (short)0x3F80; v[4] = lo;
            }
            ax[r] = v;
        }
        unsigned hn2[4][8];
        lstm_step_sub<0>(hbuf, cbt, Wb, WxS, ax, hn2, l, l15, lq);
        lstm_step_sub<1>(hbuf, cbt, Wb, WxS, ax, hn2, l, l15, lq);
        lstm_step_sub<2>(hbuf, cbt, Wb, WxS, ax, hn2, l, l15, lq);
        lstm_step_sub<3>(hbuf, cbt, Wb, WxS, ax, hn2, l, l15, lq);
        __syncthreads();   // all reads of old h complete
        #pragma unroll
        for (int s = 0; s < 4; s++) {
            int j = w * 64 + s * 16 + l15;
            #pragma unroll
            for (int r = 0; r < 4; r++)
                #pragma unroll
                for (int pi = 0; pi < 2; pi++) {
                    unsigned v = hn2[s][r * 2 + pi];
                    int row0 = r * 16 + lq * 4 + pi * 2;
                    int row1 = row0 + 1;
                    hbuf[SWZ(row0, row0 * 512 + j)] = (short)(v & 0xffffu);
                    hbuf[SWZ(row1, row1 * 512 + j)] = (short)(v >> 16);
                }
        }
        __syncthreads();   // new h visible
    }

    // final h -> Z columns [f*512, f*512+512)
    {
        int row = tid >> 3, cg = (tid & 7) * 64;
        short* dst = Z + (size_t)(b0 + row) * ZW_ + f * H_ + cg;
        #pragma unroll
        for (int i = 0; i < 64; i += 8) {
            int elem = SWZ(row, row * 512 + cg + i);
            *(short8*)(dst + i) = *(const short8*)&hbuf[elem];
        }
    }
}

// ---------------------------------------------------------------- static MLP
__global__ void k_static(const float* __restrict__ X,
                         const float* __restrict__ sW1T, const float* __restrict__ sb1,
                         const float* __restrict__ sW2T, const float* __restrict__ sb2,
                         const float* __restrict__ sW3T, const float* __restrict__ sb3,
                         short* __restrict__ Z) {
    __shared__ float xs[64], s1[256], s2[256];
    int row = blockIdx.x, tid = threadIdx.x;
    if (tid < 64) xs[tid] = X[row * 64 + tid];
    __syncthreads();
    float a = sb1[tid];
    for (int i = 0; i < 64; i++) a += xs[i] * sW1T[i * 256 + tid];
    s1[tid] = fmaxf(a, 0.f);
    __syncthreads();
    a = sb2[tid];
    for (int i = 0; i < 256; i++) a += s1[i] * sW2T[i * 256 + tid];
    s2[tid] = fmaxf(a, 0.f);
    __syncthreads();
    a = sb3[tid];
    for (int i = 0; i < 256; i++) a += s2[i] * sW3T[i * 256 + tid];
    Z[(size_t)row * ZW_ + F_ * H_ + tid] = f2bf(fmaxf(a, 0.f));
}

// ---------------------------------------------------------------- GEMM + bias + relu
__global__ __launch_bounds__(256, 2)
void k_gemm_relu(const short* __restrict__ A, const short* __restrict__ W,
                 const float* __restrict__ bias, short* __restrict__ C,
                 int M, int N, int K) {
    __shared__ __align__(16) short at[128 * 128];
    int tid = threadIdx.x;
    int wid = tid >> 6, l = tid & 63, l15 = l & 15, lq = l >> 4;
    int wm = wid >> 1, wn = wid & 1;
    int mb = blockIdx.x * 128, nb = blockIdx.y * 128;
    f32x4 acc[4][4];   // [colfrag][rowfrag]
    #pragma unroll
    for (int n = 0; n < 4; n++)
        #pragma unroll
        for (int r = 0; r < 4; r++)
            acc[n][r] = (f32x4){0.f, 0.f, 0.f, 0.f};

    #pragma unroll 1
    for (int kc = 0; kc < K; kc += 128) {
        {   // stage A tile 128x128 bf16 (swizzled)
            int row = tid >> 1, off = (tid & 1) * 64;
            const short* src = A + (size_t)(mb + row) * K + kc + off;
            #pragma unroll
            for (int i = 0; i < 64; i += 8) {
                short8 v = *(const short8*)(src + i);
                int elem = (row * 128 + off + i) ^ ((row & 7) << 3);
                *(short8*)&at[elem] = v;
            }
        }
        __syncthreads();
        #pragma unroll
        for (int kk = 0; kk < 4; kk++) {
            int k = kk * 32 + lq * 8;
            short8 a[4], bfr[4];
            #pragma unroll
            for (int r = 0; r < 4; r++) {
                int row = wm * 64 + 16 * r + l15;
                int elem = (row * 128 + k) ^ ((row & 7) << 3);
                a[r] = *(const short8*)&at[elem];
            }
            #pragma unroll
            for (int n = 0; n < 4; n++)
                bfr[n] = *(const short8*)(W + (size_t)(nb + wn * 64 + 16 * n + l15) * K + kc + k);
            #pragma unroll
            for (int n = 0; n < 4; n++)
                #pragma unroll
                for (int r = 0; r < 4; r++)
                    acc[n][r] = __builtin_amdgcn_mfma_f32_16x16x32_bf16(a[r], bfr[n], acc[n][r], 0, 0, 0);
        }
        __syncthreads();
    }
    #pragma unroll
    for (int n = 0; n < 4; n++) {
        int col = nb + wn * 64 + 16 * n + l15;
        float bv = bias[col];
        #pragma unroll
        for (int r = 0; r < 4; r++)
            #pragma unroll
            for (int p = 0; p < 4; p++) {
                int row = mb + wm * 64 + 16 * r + lq * 4 + p;
                C[(size_t)row * N + col] = f2bf(fmaxf(acc[n][r][p] + bv, 0.f));
            }
    }
}

// ---------------------------------------------------------------- head layer 3 + BCE partials
__global__ void k_head3(const short* __restrict__ Z2, const float* __restrict__ W3,
                        const float* __restrict__ b3, const float* __restrict__ tgt,
                        float* __restrict__ out, float* __restrict__ lsum) {
    __shared__ float ls[32];
    int tid = threadIdx.x, wv = tid >> 6, l = tid & 63;
    int rsub = l >> 3, ks = l & 7;
    int row = blockIdx.x * 32 + wv * 8 + rsub;
    const short* z = Z2 + (size_t)row * 1024 + ks * 128;
    const float* w0 = W3 + ks * 128;
    const float* w1 = W3 + 1024 + ks * 128;
    float a0 = 0.f, a1 = 0.f;
    for (int i = 0; i < 128; i += 8) {
        short8 zv = *(const short8*)(z + i);
        #pragma unroll
        for (int j = 0; j < 8; j++) {
            float zf = bf2f(zv[j]);
            a0 += zf * w0[i + j];
            a1 += zf * w1[i + j];
        }
    }
    a0 += __shfl_xor(a0, 1); a0 += __shfl_xor(a0, 2); a0 += __shfl_xor(a0, 4);
    a1 += __shfl_xor(a1, 1); a1 += __shfl_xor(a1, 2); a1 += __shfl_xor(a1, 4);
    if (ks == 0) {
        float p0 = fmaxf(a0 + b3[0], 0.f), p1 = fmaxf(a1 + b3[1], 0.f);
        out[row * 2] = p0; out[row * 2 + 1] = p1;
        float t0 = tgt[row * 2], t1 = tgt[row * 2 + 1];
        ls[wv * 8 + rsub] = (p0 - p0 * t0 + __logf(1.f + __expf(-p0)))
                          + (p1 - p1 * t1 + __logf(1.f + __expf(-p1)));
    }
    __syncthreads();
    if (tid == 0) {
        float s = 0.f;
        for (int i = 0; i < 32; i++) s += ls[i];
        lsum[blockIdx.x] = s;
    }
}

__global__ void k_loss_final(const float* __restrict__ lsum, float* __restrict__ out) {
    int l = threadIdx.x;   // 64 threads
    float v = lsum[l] + lsum[l + 64];
    for (int m = 1; m < 64; m <<= 1) v += __shfl_xor(v, m);
    if (l == 0) out[B_ * 2] = v / (float)(B_ * 2);
}

// ---------------------------------------------------------------- launch
extern "C" void kernel_launch(void* const* d_in, const int* in_sizes, int n_in,
                              void* d_out, int out_size, void* d_ws, size_t ws_size,
                              hipStream_t stream) {
    const float* sfeat = (const float*)d_in[0];
    const float* tfeat = (const float*)d_in[1];
    const float* tmask = (const float*)d_in[2];
    const float* tgt   = (const float*)d_in[3];
    const float* h0    = (const float*)d_in[4];
    const float* c0    = (const float*)d_in[5];
    const float* Wih   = (const float*)d_in[6];
    const float* Whh   = (const float*)d_in[7];
    const float* bih   = (const float*)d_in[8];
    const float* bhh   = (const float*)d_in[9];
    const float* sW1   = (const float*)d_in[10];
    const float* sb1   = (const float*)d_in[11];
    const float* sW2   = (const float*)d_in[12];
    const float* sb2   = (const float*)d_in[13];
    const float* sW3   = (const float*)d_in[14];
    const float* sb3   = (const float*)d_in[15];
    const float* dW1   = (const float*)d_in[16];
    const float* db1   = (const float*)d_in[17];
    const float* dW2   = (const float*)d_in[18];
    const float* db2   = (const float*)d_in[19];
    const float* dW3   = (const float*)d_in[20];
    const float* db3   = (const float*)d_in[21];

    char* ws = (char*)d_ws;
    size_t off = 0;
    short* Wpk    = (short*)(ws + off); off += (size_t)F_ * GH_ * H_ * 2;       // 25,165,824
    short* Wx     = (short*)(ws + off); off += (size_t)F_ * 32 * 4 * 512 * 2;   //  1,572,864
    short* dW1_bf = (short*)(ws + off); off += (size_t)1024 * ZW_ * 2;          // 13,107,200
    short* dW2_bf = (short*)(ws + off); off += (size_t)1024 * 1024 * 2;         //  2,097,152
    float* sW1T   = (float*)(ws + off); off += (size_t)64 * 256 * 4;
    float* sW2T   = (float*)(ws + off); off += (size_t)256 * 256 * 4;
    float* sW3T   = (float*)(ws + off); off += (size_t)256 * 256 * 4;
    short* Z      = (short*)(ws + off); off += (size_t)B_ * ZW_ * 2;            // 52,428,800
    short* Z1     = (short*)(ws + off); off += (size_t)B_ * 1024 * 2;
    short* Z2     = (short*)(ws + off); off += (size_t)B_ * 1024 * 2;
    float* lsum   = (float*)(ws + off); off += 128 * 4;

    float* out = (float*)d_out;

    k_convert<<<2048, 256, 0, stream>>>(Whh, dW1, dW2, bih, bhh, Wih, sW1, sW2, sW3,
                                        Wpk, Wx, dW1_bf, dW2_bf, sW1T, sW2T, sW3T);
    k_lstm<<<768, 512, 0, stream>>>(Wpk, Wx, tfeat, tmask, h0, c0, Z);
    k_static<<<4096, 256, 0, stream>>>(sfeat, sW1T, sb1, sW2T, sb2, sW3T, sb3, Z);
    k_gemm_relu<<<dim3(32, 8), 256, 0, stream>>>(Z, dW1_bf, db1, Z1, B_, 1024, ZW_);
    k_gemm_relu<<<dim3(32, 8), 256, 0, stream>>>(Z1, dW2_bf, db2, Z2, B_, 1024, 1024);
    k_head3<<<128, 256, 0, stream>>>(Z2, dW3, db3, tgt, out, lsum);
    k_loss_final<<<1, 64, 0, stream>>>(lsum, out);
}

// Round 6
// 26132.971 us; speedup vs baseline: 1.2100x; 1.2100x over previous
//
#include <hip/hip_runtime.h>
#include <hip/hip_bf16.h>

#define B_ 4096
#define T_ 24
#define F_ 12
#define H_ 512
#define GH_ 2048   // 4*H
#define ZW_ 6400   // F*H + 256

// XOR swizzle (16B-fragment granularity, bijective within a 512-short row)
#define SWZ(row, elem) ((elem) ^ (((row) & 15) << 3))

typedef __attribute__((ext_vector_type(8))) short short8;
typedef __attribute__((ext_vector_type(4))) float f32x4;

__device__ __forceinline__ short f2bf(float f) {
    union { float f; unsigned int u; } v; v.f = f;
    unsigned int u = v.u;
    unsigned int r = (u + 0x7FFFu + ((u >> 16) & 1u)) >> 16;
    return (short)r;
}
__device__ __forceinline__ float bf2f(short b) {
    union { unsigned int u; float f; } v; v.u = ((unsigned int)(unsigned short)b) << 16;
    return v.f;
}
__device__ __forceinline__ float fastrcp(float x) { return __builtin_amdgcn_rcpf(x); }
__device__ __forceinline__ float sigm(float x) { return fastrcp(1.f + __expf(-x)); }
__device__ __forceinline__ float tanh_(float x) { return 1.f - 2.f * fastrcp(__expf(2.f * x) + 1.f); }

// ---------------------------------------------------------------- convert
// Whh packed to MFMA B-fragment order:
//   Wpk[(((f*32 + jb)*16 + kk)*4 + g)*512 + l*8 + e]
//     = bf16( Whh[f][g*512 + jb*16 + (l&15)][kk*32 + (l>>4)*8 + e] )
__global__ void k_convert(const float* Whh, const float* dW1, const float* dW2,
                          const float* bih, const float* bhh,
                          const float* sW1, const float* sW2, const float* sW3,
                          short* Wpk, short* odW1, short* odW2, float* obias,
                          float* sW1T, float* sW2T, float* sW3T) {
    const int N2 = 1024 * ZW_;             // 6,553,600
    const int N3 = 1024 * 1024;
    const int NB = F_ * GH_;
    const int N4 = F_ * 32 * 16 * 4 * 64;  // Wpk fragments of 8
    int idx = blockIdx.x * blockDim.x + threadIdx.x;
    int stride = gridDim.x * blockDim.x;
    for (int i = idx; i < N4; i += stride) {
        int l  = i & 63;
        int g  = (i >> 6) & 3;
        int kk = (i >> 8) & 15;
        int jb = (i >> 12) & 31;
        int f  = i >> 17;
        int row = g * 512 + jb * 16 + (l & 15);
        int col = kk * 32 + (l >> 4) * 8;
        const float* src = Whh + ((size_t)f * GH_ + row) * H_ + col;
        short tmp[8];
        #pragma unroll
        for (int e = 0; e < 8; e++) tmp[e] = f2bf(src[e]);
        *(short8*)(Wpk + (size_t)i * 8) = *(short8*)tmp;
    }
    for (int i = idx; i < N2; i += stride) odW1[i] = f2bf(dW1[i]);
    for (int i = idx; i < N3; i += stride) odW2[i] = f2bf(dW2[i]);
    for (int i = idx; i < NB; i += stride) obias[i] = bih[i] + bhh[i];
    for (int i = idx; i < 64 * 256; i += stride) {      // sW1T[i][t] = sW1[t][i]
        int r = i >> 8, t = i & 255;
        sW1T[i] = sW1[t * 64 + r];
    }
    for (int i = idx; i < 256 * 256; i += stride) {
        int r = i >> 8, t = i & 255;
        sW2T[i] = sW2[t * 256 + r];
        sW3T[i] = sW3[t * 256 + r];
    }
}

// ---------------------------------------------------------------- LSTM
// grid 1536 (12 features x 128 batch-tiles of 32 rows), 512 threads (8 waves).
// Per-thread live state sized to FIT the 128-VGPR cap by construction:
//   c = 32 f32 (2 rowfrags), acc = 32, frags = 24, misc ~25  ->  ~113 regs.
// h double-buffered bf16 in LDS (2x32KB, swizzled); one barrier per step.
// LDS ~65KB -> 2 blocks/CU = 4 waves/SIMD (launch_bounds(512,4) caps at 128).
__global__ __launch_bounds__(512, 4)
void k_lstm(const short* __restrict__ Wpk,   // packed, see k_convert
            const float* __restrict__ Wih,   // [F][2048][2]
            const float* __restrict__ bias,  // [F][2048] (b_ih+b_hh)
            const float* __restrict__ tfeat, // [B][T][F]
            const float* __restrict__ tmask,
            const float* __restrict__ h0,    // [F][B][H]
            const float* __restrict__ c0,
            short* __restrict__ Z)           // [B][6400] bf16
{
    __shared__ __align__(16) short hbuf[2][32 * 512];   // 2 x 32KB
    __shared__ float xv[2][32], xm[2][32];

    int bid = blockIdx.x;
    int wg = (bid & 7) * 192 + (bid >> 3);   // XCD swizzle (1536 = 8*192, bijective)
    int f = wg >> 7;
    int b0 = (wg & 127) * 32;
    int tid = threadIdx.x;
    int w = tid >> 6;
    int l = tid & 63;
    int l15 = l & 15, lq = l >> 4;

    // stage h0 -> hbuf[0] (bf16, swizzled): 32 rows x 512 cols
    {
        int row = tid >> 4, cg = (tid & 15) * 32;
        const float* src = h0 + ((size_t)f * B_ + b0 + row) * H_ + cg;
        #pragma unroll
        for (int i = 0; i < 32; i += 8) {
            short tmp[8];
            #pragma unroll
            for (int j = 0; j < 8; j++) tmp[j] = f2bf(src[i + j]);
            int elem = SWZ(row, row * 512 + cg + i);
            *(short8*)&hbuf[0][elem] = *(short8*)tmp;
        }
    }
    if (tid < 32)       xv[0][tid]      = tfeat[(size_t)(b0 + tid) * (T_ * F_) + f];
    else if (tid < 64)  xm[0][tid - 32] = tmask[(size_t)(b0 + tid - 32) * (T_ * F_) + f];

    // c0 -> registers: c[s][r][p], rows r*16+lq*4+p (r=0,1), col j
    float c[4][2][4];
    #pragma unroll
    for (int s = 0; s < 4; s++) {
        int j = w * 64 + s * 16 + l15;
        #pragma unroll
        for (int r = 0; r < 2; r++) {
            const float* cp = c0 + ((size_t)f * B_ + b0 + r * 16 + lq * 4) * H_ + j;
            #pragma unroll
            for (int p = 0; p < 4; p++) c[s][r][p] = cp[(size_t)p * H_];
        }
    }
    __syncthreads();

    const short* Wb    = Wpk + (((size_t)f * 32 + w * 4) << 15);
    const float* Wihf  = Wih + (size_t)f * GH_ * 2;
    const float* biasf = bias + (size_t)f * GH_;

    #pragma unroll 1
    for (int t = 0; t < T_; t++) {
        int rb = t & 1, wb = rb ^ 1;
        // prefetch x(t+1) into the other buffer (ordered by end-of-step barrier)
        if (t < T_ - 1) {
            if (tid < 32)      xv[wb][tid]      = tfeat[(size_t)(b0 + tid) * (T_ * F_) + (t + 1) * F_ + f];
            else if (tid < 64) xm[wb][tid - 32] = tmask[(size_t)(b0 + tid - 32) * (T_ * F_) + (t + 1) * F_ + f];
        }
        #pragma unroll
        for (int s = 0; s < 4; s++) {
            int j = w * 64 + s * 16 + l15;
            const short* Ws = Wb + ((size_t)s << 15) + l * 8;
            // acc init with bias + W_ih * x (fp32 VALU; tiny, L1-hot loads)
            f32x4 acc[4][2];
            #pragma unroll
            for (int g = 0; g < 4; g++) {
                int col = g * 512 + j;
                float bs = biasf[col];
                float w0 = Wihf[col * 2], w1 = Wihf[col * 2 + 1];
                #pragma unroll
                for (int r = 0; r < 2; r++)
                    #pragma unroll
                    for (int p = 0; p < 4; p++) {
                        int row = r * 16 + lq * 4 + p;
                        acc[g][r][p] = bs + w0 * xv[rb][row] + w1 * xm[rb][row];
                    }
            }
            // K loop: 512 = 16 x 32
            #pragma unroll
            for (int kk = 0; kk < 16; kk++) {
                int k = kk * 32 + lq * 8;
                short8 a[2], bfr[4];
                #pragma unroll
                for (int r = 0; r < 2; r++) {
                    int row = r * 16 + l15;
                    int elem = SWZ(row, row * 512 + k);
                    a[r] = *(const short8*)&hbuf[rb][elem];
                }
                #pragma unroll
                for (int g = 0; g < 4; g++)
                    bfr[g] = *(const short8*)(Ws + (kk * 4 + g) * 512);
                #pragma unroll
                for (int g = 0; g < 4; g++)
                    #pragma unroll
                    for (int r = 0; r < 2; r++)
                        acc[g][r] = __builtin_amdgcn_mfma_f32_16x16x32_bf16(a[r], bfr[g], acc[g][r], 0, 0, 0);
            }
            // cell update + h write (fp32 nonlinearity, bf16 h)
            #pragma unroll
            for (int r = 0; r < 2; r++)
                #pragma unroll
                for (int p = 0; p < 4; p++) {
                    float iv = acc[0][r][p], fv = acc[1][r][p];
                    float gv = acc[2][r][p], ov = acc[3][r][p];
                    float cn = sigm(fv) * c[s][r][p] + sigm(iv) * tanh_(gv);
                    c[s][r][p] = cn;
                    float hn = sigm(ov) * tanh_(cn);
                    int row = r * 16 + lq * 4 + p;
                    int elem = SWZ(row, row * 512 + j);
                    hbuf[wb][elem] = f2bf(hn);
                }
        }
        __syncthreads();
    }

    // final h (in hbuf[0], T even) -> Z columns [f*512, f*512+512)
    {
        int row = tid >> 4, cg = (tid & 15) * 32;
        short* dst = Z + (size_t)(b0 + row) * ZW_ + f * H_ + cg;
        #pragma unroll
        for (int i = 0; i < 32; i += 8) {
            int elem = SWZ(row, row * 512 + cg + i);
            *(short8*)(dst + i) = *(const short8*)&hbuf[0][elem];
        }
    }
}

// ---------------------------------------------------------------- static MLP
__global__ void k_static(const float* __restrict__ X,
                         const float* __restrict__ sW1T, const float* __restrict__ sb1,
                         const float* __restrict__ sW2T, const float* __restrict__ sb2,
                         const float* __restrict__ sW3T, const float* __restrict__ sb3,
                         short* __restrict__ Z) {
    __shared__ float xs[64], s1[256], s2[256];
    int row = blockIdx.x, tid = threadIdx.x;
    if (tid < 64) xs[tid] = X[row * 64 + tid];
    __syncthreads();
    float a = sb1[tid];
    for (int i = 0; i < 64; i++) a += xs[i] * sW1T[i * 256 + tid];
    s1[tid] = fmaxf(a, 0.f);
    __syncthreads();
    a = sb2[tid];
    for (int i = 0; i < 256; i++) a += s1[i] * sW2T[i * 256 + tid];
    s2[tid] = fmaxf(a, 0.f);
    __syncthreads();
    a = sb3[tid];
    for (int i = 0; i < 256; i++) a += s2[i] * sW3T[i * 256 + tid];
    Z[(size_t)row * ZW_ + F_ * H_ + tid] = f2bf(fmaxf(a, 0.f));
}

// ---------------------------------------------------------------- GEMM + bias + relu
__global__ __launch_bounds__(256, 2)
void k_gemm_relu(const short* __restrict__ A, const short* __restrict__ W,
                 const float* __restrict__ bias, short* __restrict__ C,
                 int M, int N, int K) {
    __shared__ __align__(16) short at[128 * 128];
    int tid = threadIdx.x;
    int wid = tid >> 6, l = tid & 63, l15 = l & 15, lq = l >> 4;
    int wm = wid >> 1, wn = wid & 1;
    int mb = blockIdx.x * 128, nb = blockIdx.y * 128;
    f32x4 acc[4][4];   // [colfrag][rowfrag]
    #pragma unroll
    for (int n = 0; n < 4; n++)
        #pragma unroll
        for (int r = 0; r < 4; r++)
            acc[n][r] = (f32x4){0.f, 0.f, 0.f, 0.f};

    #pragma unroll 1
    for (int kc = 0; kc < K; kc += 128) {
        {   // stage A tile 128x128 bf16 (swizzled)
            int row = tid >> 1, off = (tid & 1) * 64;
            const short* src = A + (size_t)(mb + row) * K + kc + off;
            #pragma unroll
            for (int i = 0; i < 64; i += 8) {
                short8 v = *(const short8*)(src + i);
                int elem = (row * 128 + off + i) ^ ((row & 7) << 3);
                *(short8*)&at[elem] = v;
            }
        }
        __syncthreads();
        #pragma unroll
        for (int kk = 0; kk < 4; kk++) {
            int k = kk * 32 + lq * 8;
            short8 a[4], bfr[4];
            #pragma unroll
            for (int r = 0; r < 4; r++) {
                int row = wm * 64 + 16 * r + l15;
                int elem = (row * 128 + k) ^ ((row & 7) << 3);
                a[r] = *(const short8*)&at[elem];
            }
            #pragma unroll
            for (int n = 0; n < 4; n++)
                bfr[n] = *(const short8*)(W + (size_t)(nb + wn * 64 + 16 * n + l15) * K + kc + k);
            #pragma unroll
            for (int n = 0; n < 4; n++)
                #pragma unroll
                for (int r = 0; r < 4; r++)
                    acc[n][r] = __builtin_amdgcn_mfma_f32_16x16x32_bf16(a[r], bfr[n], acc[n][r], 0, 0, 0);
        }
        __syncthreads();
    }
    #pragma unroll
    for (int n = 0; n < 4; n++) {
        int col = nb + wn * 64 + 16 * n + l15;
        float bv = bias[col];
        #pragma unroll
        for (int r = 0; r < 4; r++)
            #pragma unroll
            for (int p = 0; p < 4; p++) {
                int row = mb + wm * 64 + 16 * r + lq * 4 + p;
                C[(size_t)row * N + col] = f2bf(fmaxf(acc[n][r][p] + bv, 0.f));
            }
    }
}

// ---------------------------------------------------------------- head layer 3 + BCE partials
__global__ void k_head3(const short* __restrict__ Z2, const float* __restrict__ W3,
                        const float* __restrict__ b3, const float* __restrict__ tgt,
                        float* __restrict__ out, float* __restrict__ lsum) {
    __shared__ float ls[32];
    int tid = threadIdx.x, wv = tid >> 6, l = tid & 63;
    int rsub = l >> 3, ks = l & 7;
    int row = blockIdx.x * 32 + wv * 8 + rsub;
    const short* z = Z2 + (size_t)row * 1024 + ks * 128;
    const float* w0 = W3 + ks * 128;
    const float* w1 = W3 + 1024 + ks * 128;
    float a0 = 0.f, a1 = 0.f;
    for (int i = 0; i < 128; i += 8) {
        short8 zv = *(const short8*)(z + i);
        #pragma unroll
        for (int j = 0; j < 8; j++) {
            float zf = bf2f(zv[j]);
            a0 += zf * w0[i + j];
            a1 += zf * w1[i + j];
        }
    }
    a0 += __shfl_xor(a0, 1); a0 += __shfl_xor(a0, 2); a0 += __shfl_xor(a0, 4);
    a1 += __shfl_xor(a1, 1); a1 += __shfl_xor(a1, 2); a1 += __shfl_xor(a1, 4);
    if (ks == 0) {
        float p0 = fmaxf(a0 + b3[0], 0.f), p1 = fmaxf(a1 + b3[1], 0.f);
        out[row * 2] = p0; out[row * 2 + 1] = p1;
        float t0 = tgt[row * 2], t1 = tgt[row * 2 + 1];
        ls[wv * 8 + rsub] = (p0 - p0 * t0 + __logf(1.f + __expf(-p0)))
                          + (p1 - p1 * t1 + __logf(1.f + __expf(-p1)));
    }
    __syncthreads();
    if (tid == 0) {
        float s = 0.f;
        for (int i = 0; i < 32; i++) s += ls[i];
        lsum[blockIdx.x] = s;
    }
}

__global__ void k_loss_final(const float* __restrict__ lsum, float* __restrict__ out) {
    int l = threadIdx.x;   // 64 threads
    float v = lsum[l] + lsum[l + 64];
    for (int m = 1; m < 64; m <<= 1) v += __shfl_xor(v, m);
    if (l == 0) out[B_ * 2] = v / (float)(B_ * 2);
}

// ---------------------------------------------------------------- launch
extern "C" void kernel_launch(void* const* d_in, const int* in_sizes, int n_in,
                              void* d_out, int out_size, void* d_ws, size_t ws_size,
                              hipStream_t stream) {
    const float* sfeat = (const float*)d_in[0];
    const float* tfeat = (const float*)d_in[1];
    const float* tmask = (const float*)d_in[2];
    const float* tgt   = (const float*)d_in[3];
    const float* h0    = (const float*)d_in[4];
    const float* c0    = (const float*)d_in[5];
    const float* Wih   = (const float*)d_in[6];
    const float* Whh   = (const float*)d_in[7];
    const float* bih   = (const float*)d_in[8];
    const float* bhh   = (const float*)d_in[9];
    const float* sW1   = (const float*)d_in[10];
    const float* sb1   = (const float*)d_in[11];
    const float* sW2   = (const float*)d_in[12];
    const float* sb2   = (const float*)d_in[13];
    const float* sW3   = (const float*)d_in[14];
    const float* sb3   = (const float*)d_in[15];
    const float* dW1   = (const float*)d_in[16];
    const float* db1   = (const float*)d_in[17];
    const float* dW2   = (const float*)d_in[18];
    const float* db2   = (const float*)d_in[19];
    const float* dW3   = (const float*)d_in[20];
    const float* db3   = (const float*)d_in[21];

    char* ws = (char*)d_ws;
    size_t off = 0;
    short* Wpk    = (short*)(ws + off); off += (size_t)F_ * GH_ * H_ * 2;       // 25,165,824
    short* dW1_bf = (short*)(ws + off); off += (size_t)1024 * ZW_ * 2;          // 13,107,200
    short* dW2_bf = (short*)(ws + off); off += (size_t)1024 * 1024 * 2;         //  2,097,152
    float* biasb  = (float*)(ws + off); off += (size_t)F_ * GH_ * 4;            //     98,304
    float* sW1T   = (float*)(ws + off); off += (size_t)64 * 256 * 4;
    float* sW2T   = (float*)(ws + off); off += (size_t)256 * 256 * 4;
    float* sW3T   = (float*)(ws + off); off += (size_t)256 * 256 * 4;
    short* Z      = (short*)(ws + off); off += (size_t)B_ * ZW_ * 2;            // 52,428,800
    short* Z1     = (short*)(ws + off); off += (size_t)B_ * 1024 * 2;
    short* Z2     = (short*)(ws + off); off += (size_t)B_ * 1024 * 2;
    float* lsum   = (float*)(ws + off); off += 128 * 4;

    float* out = (float*)d_out;

    k_convert<<<2048, 256, 0, stream>>>(Whh, dW1, dW2, bih, bhh, sW1, sW2, sW3,
                                        Wpk, dW1_bf, dW2_bf, biasb, sW1T, sW2T, sW3T);
    k_lstm<<<1536, 512, 0, stream>>>(Wpk, Wih, biasb, tfeat, tmask, h0, c0, Z);
    k_static<<<4096, 256, 0, stream>>>(sfeat, sW1T, sb1, sW2T, sb2, sW3T, sb3, Z);
    k_gemm_relu<<<dim3(32, 8), 256, 0, stream>>>(Z, dW1_bf, db1, Z1, B_, 1024, ZW_);
    k_gemm_relu<<<dim3(32, 8), 256, 0, stream>>>(Z1, dW2_bf, db2, Z2, B_, 1024, 1024);
    k_head3<<<128, 256, 0, stream>>>(Z2, dW3, db3, tgt, out, lsum);
    k_loss_final<<<1, 64, 0, stream>>>(lsum, out);
}

// Round 7
// 20572.545 us; speedup vs baseline: 1.5370x; 1.2703x over previous
//
#include <hip/hip_runtime.h>
#include <hip/hip_bf16.h>

#define B_ 4096
#define T_ 24
#define F_ 12
#define H_ 512
#define GH_ 2048   // 4*H
#define ZW_ 6400   // F*H + 256

// XOR swizzle (16B-fragment granularity, bijective within a 512-short row)
#define SWZ(row, elem) ((elem) ^ (((row) & 15) << 3))

typedef __attribute__((ext_vector_type(8))) short short8;
typedef __attribute__((ext_vector_type(4))) float f32x4;

__device__ __forceinline__ short f2bf(float f) {
    union { float f; unsigned int u; } v; v.f = f;
    unsigned int u = v.u;
    unsigned int r = (u + 0x7FFFu + ((u >> 16) & 1u)) >> 16;
    return (short)r;
}
__device__ __forceinline__ float bf2f(short b) {
    union { unsigned int u; float f; } v; v.u = ((unsigned int)(unsigned short)b) << 16;
    return v.f;
}
__device__ __forceinline__ float fastrcp(float x) { return __builtin_amdgcn_rcpf(x); }
__device__ __forceinline__ float sigm(float x) { return fastrcp(1.f + __expf(-x)); }
__device__ __forceinline__ float tanh_(float x) { return 1.f - 2.f * fastrcp(__expf(2.f * x) + 1.f); }

// ---------------------------------------------------------------- convert
// Whh packed to MFMA B-fragment order:
//   Wpk[(((f*32 + jb)*16 + kk)*4 + g)*512 + l*8 + e]
//     = bf16( Whh[f][g*512 + jb*16 + (l&15)][kk*32 + (l>>4)*8 + e] )
__global__ void k_convert(const float* Whh, const float* dW1, const float* dW2,
                          const float* bih, const float* bhh,
                          const float* sW1, const float* sW2, const float* sW3,
                          short* Wpk, short* odW1, short* odW2, float* obias,
                          float* sW1T, float* sW2T, float* sW3T) {
    const int N2 = 1024 * ZW_;             // 6,553,600
    const int N3 = 1024 * 1024;
    const int NB = F_ * GH_;
    const int N4 = F_ * 32 * 16 * 4 * 64;  // Wpk fragments of 8
    int idx = blockIdx.x * blockDim.x + threadIdx.x;
    int stride = gridDim.x * blockDim.x;
    for (int i = idx; i < N4; i += stride) {
        int l  = i & 63;
        int g  = (i >> 6) & 3;
        int kk = (i >> 8) & 15;
        int jb = (i >> 12) & 31;
        int f  = i >> 17;
        int row = g * 512 + jb * 16 + (l & 15);
        int col = kk * 32 + (l >> 4) * 8;
        const float* src = Whh + ((size_t)f * GH_ + row) * H_ + col;
        short tmp[8];
        #pragma unroll
        for (int e = 0; e < 8; e++) tmp[e] = f2bf(src[e]);
        *(short8*)(Wpk + (size_t)i * 8) = *(short8*)tmp;
    }
    for (int i = idx; i < N2; i += stride) odW1[i] = f2bf(dW1[i]);
    for (int i = idx; i < N3; i += stride) odW2[i] = f2bf(dW2[i]);
    for (int i = idx; i < NB; i += stride) obias[i] = bih[i] + bhh[i];
    for (int i = idx; i < 64 * 256; i += stride) {      // sW1T[i][t] = sW1[t][i]
        int r = i >> 8, t = i & 255;
        sW1T[i] = sW1[t * 64 + r];
    }
    for (int i = idx; i < 256 * 256; i += stride) {
        int r = i >> 8, t = i & 255;
        sW2T[i] = sW2[t * 256 + r];
        sW3T[i] = sW3[t * 256 + r];
    }
}

// ---------------------------------------------------------------- LSTM
// grid 1536 (12 features x 128 batch-tiles of 32 rows), 512 threads (8 waves).
// Per-thread live state fits 128 VGPRs by construction:
//   c = 32 f32 (2 rowfrags), acc = 32, frags = 24, misc ~25  ->  ~110 regs.
// h double-buffered bf16 in LDS (2x32KB, swizzled); one barrier per step.
//
// EMPIRICAL launch-bounds mapping on this toolchain (rounds 1-6):
//   (512,2) -> 128 VGPRs   [r1-r4, 4x reproduced]
//   (512,1) -> 128 VGPRs
//   (512,4) ->  64 VGPRs   [r6: CUDA-style min-BLOCKS-per-CU semantics]
// So the 2nd arg behaves as min blocks/CU: 2 blocks x 8 waves / 4 EU =
// 4 waves/EU -> 512/4 = 128 cap. We need exactly 128; LDS 66KB allows the
// 2 blocks/CU this requests. DO NOT set 4 (halves the cap to 64 -> spill).
__global__ __launch_bounds__(512, 2)
void k_lstm(const short* __restrict__ Wpk,   // packed, see k_convert
            const float* __restrict__ Wih,   // [F][2048][2]
            const float* __restrict__ bias,  // [F][2048] (b_ih+b_hh)
            const float* __restrict__ tfeat, // [B][T][F]
            const float* __restrict__ tmask,
            const float* __restrict__ h0,    // [F][B][H]
            const float* __restrict__ c0,
            short* __restrict__ Z)           // [B][6400] bf16
{
    __shared__ __align__(16) short hbuf[2][32 * 512];   // 2 x 32KB
    __shared__ float xv[2][32], xm[2][32];

    int bid = blockIdx.x;
    int wg = (bid & 7) * 192 + (bid >> 3);   // XCD swizzle (1536 = 8*192, bijective)
    int f = wg >> 7;
    int b0 = (wg & 127) * 32;
    int tid = threadIdx.x;
    int w = tid >> 6;
    int l = tid & 63;
    int l15 = l & 15, lq = l >> 4;

    // stage h0 -> hbuf[0] (bf16, swizzled): 32 rows x 512 cols
    {
        int row = tid >> 4, cg = (tid & 15) * 32;
        const float* src = h0 + ((size_t)f * B_ + b0 + row) * H_ + cg;
        #pragma unroll
        for (int i = 0; i < 32; i += 8) {
            short tmp[8];
            #pragma unroll
            for (int j = 0; j < 8; j++) tmp[j] = f2bf(src[i + j]);
            int elem = SWZ(row, row * 512 + cg + i);
            *(short8*)&hbuf[0][elem] = *(short8*)tmp;
        }
    }
    if (tid < 32)       xv[0][tid]      = tfeat[(size_t)(b0 + tid) * (T_ * F_) + f];
    else if (tid < 64)  xm[0][tid - 32] = tmask[(size_t)(b0 + tid - 32) * (T_ * F_) + f];

    // c0 -> registers: c[s][r][p], rows r*16+lq*4+p (r=0,1), col j
    float c[4][2][4];
    #pragma unroll
    for (int s = 0; s < 4; s++) {
        int j = w * 64 + s * 16 + l15;
        #pragma unroll
        for (int r = 0; r < 2; r++) {
            const float* cp = c0 + ((size_t)f * B_ + b0 + r * 16 + lq * 4) * H_ + j;
            #pragma unroll
            for (int p = 0; p < 4; p++) c[s][r][p] = cp[(size_t)p * H_];
        }
    }
    __syncthreads();

    const short* Wb    = Wpk + (((size_t)f * 32 + w * 4) << 15);
    const float* Wihf  = Wih + (size_t)f * GH_ * 2;
    const float* biasf = bias + (size_t)f * GH_;

    #pragma unroll 1
    for (int t = 0; t < T_; t++) {
        int rb = t & 1, wb = rb ^ 1;
        // prefetch x(t+1) into the other buffer (ordered by end-of-step barrier)
        if (t < T_ - 1) {
            if (tid < 32)      xv[wb][tid]      = tfeat[(size_t)(b0 + tid) * (T_ * F_) + (t + 1) * F_ + f];
            else if (tid < 64) xm[wb][tid - 32] = tmask[(size_t)(b0 + tid - 32) * (T_ * F_) + (t + 1) * F_ + f];
        }
        #pragma unroll
        for (int s = 0; s < 4; s++) {
            int j = w * 64 + s * 16 + l15;
            const short* Ws = Wb + ((size_t)s << 15) + l * 8;
            // acc init with bias + W_ih * x (fp32 VALU; tiny, L1-hot loads)
            f32x4 acc[4][2];
            #pragma unroll
            for (int g = 0; g < 4; g++) {
                int col = g * 512 + j;
                float bs = biasf[col];
                float w0 = Wihf[col * 2], w1 = Wihf[col * 2 + 1];
                #pragma unroll
                for (int r = 0; r < 2; r++)
                    #pragma unroll
                    for (int p = 0; p < 4; p++) {
                        int row = r * 16 + lq * 4 + p;
                        acc[g][r][p] = bs + w0 * xv[rb][row] + w1 * xm[rb][row];
                    }
            }
            // K loop: 512 = 16 x 32
            #pragma unroll
            for (int kk = 0; kk < 16; kk++) {
                int k = kk * 32 + lq * 8;
                short8 a[2], bfr[4];
                #pragma unroll
                for (int r = 0; r < 2; r++) {
                    int row = r * 16 + l15;
                    int elem = SWZ(row, row * 512 + k);
                    a[r] = *(const short8*)&hbuf[rb][elem];
                }
                #pragma unroll
                for (int g = 0; g < 4; g++)
                    bfr[g] = *(const short8*)(Ws + (kk * 4 + g) * 512);
                #pragma unroll
                for (int g = 0; g < 4; g++)
                    #pragma unroll
                    for (int r = 0; r < 2; r++)
                        acc[g][r] = __builtin_amdgcn_mfma_f32_16x16x32_bf16(a[r], bfr[g], acc[g][r], 0, 0, 0);
            }
            // cell update + h write (fp32 nonlinearity, bf16 h)
            #pragma unroll
            for (int r = 0; r < 2; r++)
                #pragma unroll
                for (int p = 0; p < 4; p++) {
                    float iv = acc[0][r][p], fv = acc[1][r][p];
                    float gv = acc[2][r][p], ov = acc[3][r][p];
                    float cn = sigm(fv) * c[s][r][p] + sigm(iv) * tanh_(gv);
                    c[s][r][p] = cn;
                    float hn = sigm(ov) * tanh_(cn);
                    int row = r * 16 + lq * 4 + p;
                    int elem = SWZ(row, row * 512 + j);
                    hbuf[wb][elem] = f2bf(hn);
                }
        }
        __syncthreads();
    }

    // final h (in hbuf[0], T even) -> Z columns [f*512, f*512+512)
    {
        int row = tid >> 4, cg = (tid & 15) * 32;
        short* dst = Z + (size_t)(b0 + row) * ZW_ + f * H_ + cg;
        #pragma unroll
        for (int i = 0; i < 32; i += 8) {
            int elem = SWZ(row, row * 512 + cg + i);
            *(short8*)(dst + i) = *(const short8*)&hbuf[0][elem];
        }
    }
}

// ---------------------------------------------------------------- static MLP
__global__ void k_static(const float* __restrict__ X,
                         const float* __restrict__ sW1T, const float* __restrict__ sb1,
                         const float* __restrict__ sW2T, const float* __restrict__ sb2,
                         const float* __restrict__ sW3T, const float* __restrict__ sb3,
                         short* __restrict__ Z) {
    __shared__ float xs[64], s1[256], s2[256];
    int row = blockIdx.x, tid = threadIdx.x;
    if (tid < 64) xs[tid] = X[row * 64 + tid];
    __syncthreads();
    float a = sb1[tid];
    for (int i = 0; i < 64; i++) a += xs[i] * sW1T[i * 256 + tid];
    s1[tid] = fmaxf(a, 0.f);
    __syncthreads();
    a = sb2[tid];
    for (int i = 0; i < 256; i++) a += s1[i] * sW2T[i * 256 + tid];
    s2[tid] = fmaxf(a, 0.f);
    __syncthreads();
    a = sb3[tid];
    for (int i = 0; i < 256; i++) a += s2[i] * sW3T[i * 256 + tid];
    Z[(size_t)row * ZW_ + F_ * H_ + tid] = f2bf(fmaxf(a, 0.f));
}

// ---------------------------------------------------------------- GEMM + bias + relu
__global__ __launch_bounds__(256, 2)
void k_gemm_relu(const short* __restrict__ A, const short* __restrict__ W,
                 const float* __restrict__ bias, short* __restrict__ C,
                 int M, int N, int K) {
    __shared__ __align__(16) short at[128 * 128];
    int tid = threadIdx.x;
    int wid = tid >> 6, l = tid & 63, l15 = l & 15, lq = l >> 4;
    int wm = wid >> 1, wn = wid & 1;
    int mb = blockIdx.x * 128, nb = blockIdx.y * 128;
    f32x4 acc[4][4];   // [colfrag][rowfrag]
    #pragma unroll
    for (int n = 0; n < 4; n++)
        #pragma unroll
        for (int r = 0; r < 4; r++)
            acc[n][r] = (f32x4){0.f, 0.f, 0.f, 0.f};

    #pragma unroll 1
    for (int kc = 0; kc < K; kc += 128) {
        {   // stage A tile 128x128 bf16 (swizzled)
            int row = tid >> 1, off = (tid & 1) * 64;
            const short* src = A + (size_t)(mb + row) * K + kc + off;
            #pragma unroll
            for (int i = 0; i < 64; i += 8) {
                short8 v = *(const short8*)(src + i);
                int elem = (row * 128 + off + i) ^ ((row & 7) << 3);
                *(short8*)&at[elem] = v;
            }
        }
        __syncthreads();
        #pragma unroll
        for (int kk = 0; kk < 4; kk++) {
            int k = kk * 32 + lq * 8;
            short8 a[4], bfr[4];
            #pragma unroll
            for (int r = 0; r < 4; r++) {
                int row = wm * 64 + 16 * r + l15;
                int elem = (row * 128 + k) ^ ((row & 7) << 3);
                a[r] = *(const short8*)&at[elem];
            }
            #pragma unroll
            for (int n = 0; n < 4; n++)
                bfr[n] = *(const short8*)(W + (size_t)(nb + wn * 64 + 16 * n + l15) * K + kc + k);
            #pragma unroll
            for (int n = 0; n < 4; n++)
                #pragma unroll
                for (int r = 0; r < 4; r++)
                    acc[n][r] = __builtin_amdgcn_mfma_f32_16x16x32_bf16(a[r], bfr[n], acc[n][r], 0, 0, 0);
        }
        __syncthreads();
    }
    #pragma unroll
    for (int n = 0; n < 4; n++) {
        int col = nb + wn * 64 + 16 * n + l15;
        float bv = bias[col];
        #pragma unroll
        for (int r = 0; r < 4; r++)
            #pragma unroll
            for (int p = 0; p < 4; p++) {
                int row = mb + wm * 64 + 16 * r + lq * 4 + p;
                C[(size_t)row * N + col] = f2bf(fmaxf(acc[n][r][p] + bv, 0.f));
            }
    }
}

// ---------------------------------------------------------------- head layer 3 + BCE partials
__global__ void k_head3(const short* __restrict__ Z2, const float* __restrict__ W3,
                        const float* __restrict__ b3, const float* __restrict__ tgt,
                        float* __restrict__ out, float* __restrict__ lsum) {
    __shared__ float ls[32];
    int tid = threadIdx.x, wv = tid >> 6, l = tid & 63;
    int rsub = l >> 3, ks = l & 7;
    int row = blockIdx.x * 32 + wv * 8 + rsub;
    const short* z = Z2 + (size_t)row * 1024 + ks * 128;
    const float* w0 = W3 + ks * 128;
    const float* w1 = W3 + 1024 + ks * 128;
    float a0 = 0.f, a1 = 0.f;
    for (int i = 0; i < 128; i += 8) {
        short8 zv = *(const short8*)(z + i);
        #pragma unroll
        for (int j = 0; j < 8; j++) {
            float zf = bf2f(zv[j]);
            a0 += zf * w0[i + j];
            a1 += zf * w1[i + j];
        }
    }
    a0 += __shfl_xor(a0, 1); a0 += __shfl_xor(a0, 2); a0 += __shfl_xor(a0, 4);
    a1 += __shfl_xor(a1, 1); a1 += __shfl_xor(a1, 2); a1 += __shfl_xor(a1, 4);
    if (ks == 0) {
        float p0 = fmaxf(a0 + b3[0], 0.f), p1 = fmaxf(a1 + b3[1], 0.f);
        out[row * 2] = p0; out[row * 2 + 1] = p1;
        float t0 = tgt[row * 2], t1 = tgt[row * 2 + 1];
        ls[wv * 8 + rsub] = (p0 - p0 * t0 + __logf(1.f + __expf(-p0)))
                          + (p1 - p1 * t1 + __logf(1.f + __expf(-p1)));
    }
    __syncthreads();
    if (tid == 0) {
        float s = 0.f;
        for (int i = 0; i < 32; i++) s += ls[i];
        lsum[blockIdx.x] = s;
    }
}

__global__ void k_loss_final(const float* __restrict__ lsum, float* __restrict__ out) {
    int l = threadIdx.x;   // 64 threads
    float v = lsum[l] + lsum[l + 64];
    for (int m = 1; m < 64; m <<= 1) v += __shfl_xor(v, m);
    if (l == 0) out[B_ * 2] = v / (float)(B_ * 2);
}

// ---------------------------------------------------------------- launch
extern "C" void kernel_launch(void* const* d_in, const int* in_sizes, int n_in,
                              void* d_out, int out_size, void* d_ws, size_t ws_size,
                              hipStream_t stream) {
    const float* sfeat = (const float*)d_in[0];
    const float* tfeat = (const float*)d_in[1];
    const float* tmask = (const float*)d_in[2];
    const float* tgt   = (const float*)d_in[3];
    const float* h0    = (const float*)d_in[4];
    const float* c0    = (const float*)d_in[5];
    const float* Wih   = (const float*)d_in[6];
    const float* Whh   = (const float*)d_in[7];
    const float* bih   = (const float*)d_in[8];
    const float* bhh   = (const float*)d_in[9];
    const float* sW1   = (const float*)d_in[10];
    const float* sb1   = (const float*)d_in[11];
    const float* sW2   = (const float*)d_in[12];
    const float* sb2   = (const float*)d_in[13];
    const float* sW3   = (const float*)d_in[14];
    const float* sb3   = (const float*)d_in[15];
    const float* dW1   = (const float*)d_in[16];
    const float* db1   = (const float*)d_in[17];
    const float* dW2   = (const float*)d_in[18];
    const float* db2   = (const float*)d_in[19];
    const float* dW3   = (const float*)d_in[20];
    const float* db3   = (const float*)d_in[21];

    char* ws = (char*)d_ws;
    size_t off = 0;
    short* Wpk    = (short*)(ws + off); off += (size_t)F_ * GH_ * H_ * 2;       // 25,165,824
    short* dW1_bf = (short*)(ws + off); off += (size_t)1024 * ZW_ * 2;          // 13,107,200
    short* dW2_bf = (short*)(ws + off); off += (size_t)1024 * 1024 * 2;         //  2,097,152
    float* biasb  = (float*)(ws + off); off += (size_t)F_ * GH_ * 4;            //     98,304
    float* sW1T   = (float*)(ws + off); off += (size_t)64 * 256 * 4;
    float* sW2T   = (float*)(ws + off); off += (size_t)256 * 256 * 4;
    float* sW3T   = (float*)(ws + off); off += (size_t)256 * 256 * 4;
    short* Z      = (short*)(ws + off); off += (size_t)B_ * ZW_ * 2;            // 52,428,800
    short* Z1     = (short*)(ws + off); off += (size_t)B_ * 1024 * 2;
    short* Z2     = (short*)(ws + off); off += (size_t)B_ * 1024 * 2;
    float* lsum   = (float*)(ws + off); off += 128 * 4;

    float* out = (float*)d_out;

    k_convert<<<2048, 256, 0, stream>>>(Whh, dW1, dW2, bih, bhh, sW1, sW2, sW3,
                                        Wpk, dW1_bf, dW2_bf, biasb, sW1T, sW2T, sW3T);
    k_lstm<<<1536, 512, 0, stream>>>(Wpk, Wih, biasb, tfeat, tmask, h0, c0, Z);
    k_static<<<4096, 256, 0, stream>>>(sfeat, sW1T, sb1, sW2T, sb2, sW3T, sb3, Z);
    k_gemm_relu<<<dim3(32, 8), 256, 0, stream>>>(Z, dW1_bf, db1, Z1, B_, 1024, ZW_);
    k_gemm_relu<<<dim3(32, 8), 256, 0, stream>>>(Z1, dW2_bf, db2, Z2, B_, 1024, 1024);
    k_head3<<<128, 256, 0, stream>>>(Z2, dW3, db3, tgt, out, lsum);
    k_loss_final<<<1, 64, 0, stream>>>(lsum, out);
}

// Round 9
// 17860.555 us; speedup vs baseline: 1.7704x; 1.1518x over previous
//
#include <hip/hip_runtime.h>
#include <hip/hip_bf16.h>

#define B_ 4096
#define T_ 24
#define F_ 12
#define H_ 512
#define GH_ 2048   // 4*H
#define ZW_ 6400   // F*H + 256

// XOR swizzle (16B-fragment granularity, bijective within a 512-short row)
#define SWZ(row, elem) ((elem) ^ (((row) & 15) << 3))

typedef __attribute__((ext_vector_type(8))) short short8;
typedef __attribute__((ext_vector_type(4))) float f32x4;

__device__ __forceinline__ short f2bf(float f) {
    union { float f; unsigned int u; } v; v.f = f;
    unsigned int u = v.u;
    unsigned int r = (u + 0x7FFFu + ((u >> 16) & 1u)) >> 16;
    return (short)r;
}
__device__ __forceinline__ float bf2f(short b) {
    union { unsigned int u; float f; } v; v.u = ((unsigned int)(unsigned short)b) << 16;
    return v.f;
}
__device__ __forceinline__ float fastrcp(float x) { return __builtin_amdgcn_rcpf(x); }
__device__ __forceinline__ float sigm(float x) { return fastrcp(1.f + __expf(-x)); }
__device__ __forceinline__ float tanh_(float x) { return 1.f - 2.f * fastrcp(__expf(2.f * x) + 1.f); }

// ---------------------------------------------------------------- convert
// Whh packed to MFMA B-fragment order:
//   Wpk[(((f*32 + jb)*16 + kk)*4 + g)*512 + l*8 + e]
//     = bf16( Whh[f][g*512 + jb*16 + (l&15)][kk*32 + (l>>4)*8 + e] )
// Wx: x-part B-fragments (wx0, wx1, bias_hi, bias_lo, wx0, 0,0,0) on lq==0:
//   Wx[((f*32 + jb)*4 + g)*512 + l*8 + e]
__global__ void k_convert(const float* Whh, const float* dW1, const float* dW2,
                          const float* bih, const float* bhh, const float* Wih,
                          const float* sW1, const float* sW2, const float* sW3,
                          short* Wpk, short* Wx, short* odW1, short* odW2,
                          float* sW1T, float* sW2T, float* sW3T) {
    const int N2 = 1024 * ZW_;             // 6,553,600
    const int N3 = 1024 * 1024;
    const int N4 = F_ * 32 * 16 * 4 * 64;  // Wpk fragments of 8
    const int N5 = F_ * 32 * 4 * 64;       // Wx fragments of 8
    int idx = blockIdx.x * blockDim.x + threadIdx.x;
    int stride = gridDim.x * blockDim.x;
    for (int i = idx; i < N4; i += stride) {
        int l  = i & 63;
        int g  = (i >> 6) & 3;
        int kk = (i >> 8) & 15;
        int jb = (i >> 12) & 31;
        int f  = i >> 17;
        int row = g * 512 + jb * 16 + (l & 15);
        int col = kk * 32 + (l >> 4) * 8;
        const float* src = Whh + ((size_t)f * GH_ + row) * H_ + col;
        short tmp[8];
        #pragma unroll
        for (int e = 0; e < 8; e++) tmp[e] = f2bf(src[e]);
        *(short8*)(Wpk + (size_t)i * 8) = *(short8*)tmp;
    }
    for (int i = idx; i < N5; i += stride) {
        int l  = i & 63;
        int g  = (i >> 6) & 3;
        int jb = (i >> 8) & 31;
        int f  = i >> 13;
        short tmp[8] = {0, 0, 0, 0, 0, 0, 0, 0};
        if ((l >> 4) == 0) {
            int col = g * 512 + jb * 16 + (l & 15);
            float w0 = Wih[((size_t)f * GH_ + col) * 2];
            float w1 = Wih[((size_t)f * GH_ + col) * 2 + 1];
            float bs = bih[f * GH_ + col] + bhh[f * GH_ + col];
            short bh = f2bf(bs);
            short bl = f2bf(bs - bf2f(bh));
            short w0b = f2bf(w0);
            tmp[0] = w0b; tmp[1] = f2bf(w1); tmp[2] = bh; tmp[3] = bl; tmp[4] = w0b;
        }
        *(short8*)(Wx + (size_t)i * 8) = *(short8*)tmp;
    }
    for (int i = idx; i < N2; i += stride) odW1[i] = f2bf(dW1[i]);
    for (int i = idx; i < N3; i += stride) odW2[i] = f2bf(dW2[i]);
    for (int i = idx; i < 64 * 256; i += stride) {      // sW1T[i][t] = sW1[t][i]
        int r = i >> 8, t = i & 255;
        sW1T[i] = sW1[t * 64 + r];
    }
    for (int i = idx; i < 256 * 256; i += stride) {
        int r = i >> 8, t = i & 255;
        sW2T[i] = sW2[t * 256 + r];
        sW3T[i] = sW3[t * 256 + r];
    }
}

// ---------------------------------------------------------------- LSTM sub-step
// One j-subtile (16 cols) for one wave. c and acc are PINNED to AGPRs via
// asm "+a" (the accum half of the gfx950 unified file, which the compiler
// otherwise leaves idle while spilling arch VGPRs -- rounds 1-7 evidence:
// arch cap = half the per-wave budget whenever MFMA is present).
template<int S>
__device__ __forceinline__ void lstm_step_sub(
    const short* hread, short* hwrite,
    const short* Wb, const short* WxS,
    const float* xvp, const float* xmp,
    f32x4 (&c)[4][4],
    int l, int l15, int lq, int w)
{
    const short* Ws = Wb + ((size_t)S << 15) + l * 8;
    // build x A-fragments in place (transient): rows r*16+l15,
    // k-slots {xv_hi, xm, 1, 1, xv_lo} on lq==0 lanes only
    short8 ax[4];
    #pragma unroll
    for (int r = 0; r < 4; r++) {
        short8 v = {0, 0, 0, 0, 0, 0, 0, 0};
        if (lq == 0) {
            int row = r * 16 + l15;
            float xvf = xvp[row], xmf = xmp[row];
            short hi = f2bf(xvf);
            v[0] = hi; v[1] = f2bf(xmf);
            v[2] = (short)0x3F80; v[3] = (short)0x3F80;
            v[4] = f2bf(xvf - bf2f(hi));
        }
        ax[r] = v;
    }
    short8 bx[4];
    #pragma unroll
    for (int g = 0; g < 4; g++)
        bx[g] = *(const short8*)(WxS + S * 2048 + g * 512);
    const f32x4 zero = {0.f, 0.f, 0.f, 0.f};
    f32x4 acc[4][4];   // [gate][rowfrag] -> AGPRs
    #pragma unroll
    for (int g = 0; g < 4; g++)
        #pragma unroll
        for (int r = 0; r < 4; r++) {
            acc[g][r] = __builtin_amdgcn_mfma_f32_16x16x32_bf16(ax[r], bx[g], zero, 0, 0, 0);
            asm volatile("" : "+a"(acc[g][r]));   // pin to AGPR
        }
    // K loop: 512 = 16 x 32
    #pragma unroll
    for (int kk = 0; kk < 16; kk++) {
        int k = kk * 32 + lq * 8;
        short8 a[4], bfr[4];
        #pragma unroll
        for (int r = 0; r < 4; r++) {
            int row = r * 16 + l15;
            a[r] = *(const short8*)&hread[SWZ(row, row * 512 + k)];
        }
        #pragma unroll
        for (int g = 0; g < 4; g++)
            bfr[g] = *(const short8*)(Ws + (kk * 4 + g) * 512);
        #pragma unroll
        for (int g = 0; g < 4; g++)
            #pragma unroll
            for (int r = 0; r < 4; r++)
                acc[g][r] = __builtin_amdgcn_mfma_f32_16x16x32_bf16(a[r], bfr[g], acc[g][r], 0, 0, 0);
    }
    #pragma unroll
    for (int g = 0; g < 4; g++)
        #pragma unroll
        for (int r = 0; r < 4; r++)
            asm volatile("" : "+a"(acc[g][r]));   // keep in AGPR until epilogue
    // cell update + h write (fp32 nonlinearity, bf16 h); c stays in AGPR
    int j = w * 64 + S * 16 + l15;
    #pragma unroll
    for (int r = 0; r < 4; r++) {
        #pragma unroll
        for (int p = 0; p < 4; p++) {
            float iv = acc[0][r][p], fv = acc[1][r][p];
            float gv = acc[2][r][p], ov = acc[3][r][p];
            float cn = sigm(fv) * c[S][r][p] + sigm(iv) * tanh_(gv);
            c[S][r][p] = cn;
            float hn = sigm(ov) * tanh_(cn);
            int row = r * 16 + lq * 4 + p;
            hwrite[SWZ(row, row * 512 + j)] = f2bf(hn);
        }
        asm volatile("" : "+a"(c[S][r]));         // pin updated c back to AGPR
    }
}

// grid 768 (12 features x 64 batch-tiles of 64 rows), 512 threads (8 waves).
// h double-buffered bf16 in LDS (2x64KB, swizzled); c[16] f32x4 + acc[16]
// f32x4 in AGPRs; arch-VGPR live set ~75 << 128 cap -> no spill possible.
__global__ __launch_bounds__(512, 2)
void k_lstm(const short* __restrict__ Wpk,   // packed, see k_convert
            const short* __restrict__ Wx,    // x-part fragments
            const float* __restrict__ tfeat, // [B][T][F]
            const float* __restrict__ tmask,
            const float* __restrict__ h0,    // [F][B][H]
            const float* __restrict__ c0,
            short* __restrict__ Z)           // [B][6400] bf16
{
    __shared__ __align__(16) short hbuf[2][64 * 512];   // 2 x 64KB
    __shared__ float xv[2][64], xm[2][64];

    int bid = blockIdx.x;
    int wg = (bid & 7) * 96 + (bid >> 3);    // XCD swizzle (768 = 8*96, bijective)
    int f = wg >> 6;
    int b0 = (wg & 63) * 64;
    int tid = threadIdx.x;
    int w = tid >> 6;
    int l = tid & 63;
    int l15 = l & 15, lq = l >> 4;

    // stage h0 -> hbuf[0] (bf16, swizzled)
    {
        int row = tid >> 3, cg = (tid & 7) * 64;
        const float* src = h0 + ((size_t)f * B_ + b0 + row) * H_ + cg;
        #pragma unroll
        for (int i = 0; i < 64; i += 8) {
            short tmp[8];
            #pragma unroll
            for (int j = 0; j < 8; j++) tmp[j] = f2bf(src[i + j]);
            *(short8*)&hbuf[0][SWZ(row, row * 512 + cg + i)] = *(short8*)tmp;
        }
    }
    if (tid < 64)        xv[0][tid]      = tfeat[(size_t)(b0 + tid) * (T_ * F_) + f];
    else if (tid < 128)  xm[0][tid - 64] = tmask[(size_t)(b0 + tid - 64) * (T_ * F_) + f];

    // c0 -> AGPR-pinned registers: c[s][r] f32x4, element p
    f32x4 c[4][4];
    #pragma unroll
    for (int s = 0; s < 4; s++) {
        int j = w * 64 + s * 16 + l15;
        #pragma unroll
        for (int r = 0; r < 4; r++) {
            const float* cp = c0 + ((size_t)f * B_ + b0 + r * 16 + lq * 4) * H_ + j;
            #pragma unroll
            for (int p = 0; p < 4; p++) c[s][r][p] = cp[(size_t)p * H_];
            asm volatile("" : "+a"(c[s][r]));     // pin to AGPR
        }
    }
    __syncthreads();

    const short* Wb  = Wpk + (((size_t)f * 32 + w * 4) << 15);
    const short* WxS = Wx + ((size_t)(f * 32 + w * 4) * 4) * 512 + l * 8;

    #pragma unroll 1
    for (int t = 0; t < T_; t++) {
        int rb = t & 1, wb = rb ^ 1;
        // prefetch x(t+1) into the other buffer (ordered by end-of-step barrier)
        if (t < T_ - 1) {
            if (tid < 64)       xv[wb][tid]      = tfeat[(size_t)(b0 + tid) * (T_ * F_) + (t + 1) * F_ + f];
            else if (tid < 128) xm[wb][tid - 64] = tmask[(size_t)(b0 + tid - 64) * (T_ * F_) + (t + 1) * F_ + f];
        }
        const short* hr = hbuf[rb];
        short*       hw = hbuf[wb];
        const float* xvp = xv[rb];
        const float* xmp = xm[rb];
        lstm_step_sub<0>(hr, hw, Wb, WxS, xvp, xmp, c, l, l15, lq, w);
        lstm_step_sub<1>(hr, hw, Wb, WxS, xvp, xmp, c, l, l15, lq, w);
        lstm_step_sub<2>(hr, hw, Wb, WxS, xvp, xmp, c, l, l15, lq, w);
        lstm_step_sub<3>(hr, hw, Wb, WxS, xvp, xmp, c, l, l15, lq, w);
        __syncthreads();
    }

    // final h (in hbuf[0], T even) -> Z columns [f*512, f*512+512)
    {
        int row = tid >> 3, cg = (tid & 7) * 64;
        short* dst = Z + (size_t)(b0 + row) * ZW_ + f * H_ + cg;
        #pragma unroll
        for (int i = 0; i < 64; i += 8)
            *(short8*)(dst + i) = *(const short8*)&hbuf[0][SWZ(row, row * 512 + cg + i)];
    }
}

// ---------------------------------------------------------------- static MLP
__global__ void k_static(const float* __restrict__ X,
                         const float* __restrict__ sW1T, const float* __restrict__ sb1,
                         const float* __restrict__ sW2T, const float* __restrict__ sb2,
                         const float* __restrict__ sW3T, const float* __restrict__ sb3,
                         short* __restrict__ Z) {
    __shared__ float xs[64], s1[256], s2[256];
    int row = blockIdx.x, tid = threadIdx.x;
    if (tid < 64) xs[tid] = X[row * 64 + tid];
    __syncthreads();
    float a = sb1[tid];
    for (int i = 0; i < 64; i++) a += xs[i] * sW1T[i * 256 + tid];
    s1[tid] = fmaxf(a, 0.f);
    __syncthreads();
    a = sb2[tid];
    for (int i = 0; i < 256; i++) a += s1[i] * sW2T[i * 256 + tid];
    s2[tid] = fmaxf(a, 0.f);
    __syncthreads();
    a = sb3[tid];
    for (int i = 0; i < 256; i++) a += s2[i] * sW3T[i * 256 + tid];
    Z[(size_t)row * ZW_ + F_ * H_ + tid] = f2bf(fmaxf(a, 0.f));
}

// ---------------------------------------------------------------- GEMM + bias + relu
__global__ __launch_bounds__(256, 2)
void k_gemm_relu(const short* __restrict__ A, const short* __restrict__ W,
                 const float* __restrict__ bias, short* __restrict__ C,
                 int M, int N, int K) {
    __shared__ __align__(16) short at[128 * 128];
    int tid = threadIdx.x;
    int wid = tid >> 6, l = tid & 63, l15 = l & 15, lq = l >> 4;
    int wm = wid >> 1, wn = wid & 1;
    int mb = blockIdx.x * 128, nb = blockIdx.y * 128;
    f32x4 acc[4][4];   // [colfrag][rowfrag]
    #pragma unroll
    for (int n = 0; n < 4; n++)
        #pragma unroll
        for (int r = 0; r < 4; r++)
            acc[n][r] = (f32x4){0.f, 0.f, 0.f, 0.f};

    #pragma unroll 1
    for (int kc = 0; kc < K; kc += 128) {
        {   // stage A tile 128x128 bf16 (swizzled)
            int row = tid >> 1, off = (tid & 1) * 64;
            const short* src = A + (size_t)(mb + row) * K + kc + off;
            #pragma unroll
            for (int i = 0; i < 64; i += 8) {
                short8 v = *(const short8*)(src + i);
                int elem = (row * 128 + off + i) ^ ((row & 7) << 3);
                *(short8*)&at[elem] = v;
            }
        }
        __syncthreads();
        #pragma unroll
        for (int kk = 0; kk < 4; kk++) {
            int k = kk * 32 + lq * 8;
            short8 a[4], bfr[4];
            #pragma unroll
            for (int r = 0; r < 4; r++) {
                int row = wm * 64 + 16 * r + l15;
                int elem = (row * 128 + k) ^ ((row & 7) << 3);
                a[r] = *(const short8*)&at[elem];
            }
            #pragma unroll
            for (int n = 0; n < 4; n++)
                bfr[n] = *(const short8*)(W + (size_t)(nb + wn * 64 + 16 * n + l15) * K + kc + k);
            #pragma unroll
            for (int n = 0; n < 4; n++)
                #pragma unroll
                for (int r = 0; r < 4; r++)
                    acc[n][r] = __builtin_amdgcn_mfma_f32_16x16x32_bf16(a[r], bfr[n], acc[n][r], 0, 0, 0);
        }
        __syncthreads();
    }
    #pragma unroll
    for (int n = 0; n < 4; n++) {
        int col = nb + wn * 64 + 16 * n + l15;
        float bv = bias[col];
        #pragma unroll
        for (int r = 0; r < 4; r++)
            #pragma unroll
            for (int p = 0; p < 4; p++) {
                int row = mb + wm * 64 + 16 * r + lq * 4 + p;
                C[(size_t)row * N + col] = f2bf(fmaxf(acc[n][r][p] + bv, 0.f));
            }
    }
}

// ---------------------------------------------------------------- head layer 3 + BCE partials
__global__ void k_head3(const short* __restrict__ Z2, const float* __restrict__ W3,
                        const float* __restrict__ b3, const float* __restrict__ tgt,
                        float* __restrict__ out, float* __restrict__ lsum) {
    __shared__ float ls[32];
    int tid = threadIdx.x, wv = tid >> 6, l = tid & 63;
    int rsub = l >> 3, ks = l & 7;
    int row = blockIdx.x * 32 + wv * 8 + rsub;
    const short* z = Z2 + (size_t)row * 1024 + ks * 128;
    const float* w0 = W3 + ks * 128;
    const float* w1 = W3 + 1024 + ks * 128;
    float a0 = 0.f, a1 = 0.f;
    for (int i = 0; i < 128; i += 8) {
        short8 zv = *(const short8*)(z + i);
        #pragma unroll
        for (int j = 0; j < 8; j++) {
            float zf = bf2f(zv[j]);
            a0 += zf * w0[i + j];
            a1 += zf * w1[i + j];
        }
    }
    a0 += __shfl_xor(a0, 1); a0 += __shfl_xor(a0, 2); a0 += __shfl_xor(a0, 4);
    a1 += __shfl_xor(a1, 1); a1 += __shfl_xor(a1, 2); a1 += __shfl_xor(a1, 4);
    if (ks == 0) {
        float p0 = fmaxf(a0 + b3[0], 0.f), p1 = fmaxf(a1 + b3[1], 0.f);
        out[row * 2] = p0; out[row * 2 + 1] = p1;
        float t0 = tgt[row * 2], t1 = tgt[row * 2 + 1];
        ls[wv * 8 + rsub] = (p0 - p0 * t0 + __logf(1.f + __expf(-p0)))
                          + (p1 - p1 * t1 + __logf(1.f + __expf(-p1)));
    }
    __syncthreads();
    if (tid == 0) {
        float s = 0.f;
        for (int i = 0; i < 32; i++) s += ls[i];
        lsum[blockIdx.x] = s;
    }
}

__global__ void k_loss_final(const float* __restrict__ lsum, float* __restrict__ out) {
    int l = threadIdx.x;   // 64 threads
    float v = lsum[l] + lsum[l + 64];
    for (int m = 1; m < 64; m <<= 1) v += __shfl_xor(v, m);
    if (l == 0) out[B_ * 2] = v / (float)(B_ * 2);
}

// ---------------------------------------------------------------- launch
extern "C" void kernel_launch(void* const* d_in, const int* in_sizes, int n_in,
                              void* d_out, int out_size, void* d_ws, size_t ws_size,
                              hipStream_t stream) {
    const float* sfeat = (const float*)d_in[0];
    const float* tfeat = (const float*)d_in[1];
    const float* tmask = (const float*)d_in[2];
    const float* tgt   = (const float*)d_in[3];
    const float* h0    = (const float*)d_in[4];
    const float* c0    = (const float*)d_in[5];
    const float* Wih   = (const float*)d_in[6];
    const float* Whh   = (const float*)d_in[7];
    const float* bih   = (const float*)d_in[8];
    const float* bhh   = (const float*)d_in[9];
    const float* sW1   = (const float*)d_in[10];
    const float* sb1   = (const float*)d_in[11];
    const float* sW2   = (const float*)d_in[12];
    const float* sb2   = (const float*)d_in[13];
    const float* sW3   = (const float*)d_in[14];
    const float* sb3   = (const float*)d_in[15];
    const float* dW1   = (const float*)d_in[16];
    const float* db1   = (const float*)d_in[17];
    const float* dW2   = (const float*)d_in[18];
    const float* db2   = (const float*)d_in[19];
    const float* dW3   = (const float*)d_in[20];
    const float* db3   = (const float*)d_in[21];

    char* ws = (char*)d_ws;
    size_t off = 0;
    short* Wpk    = (short*)(ws + off); off += (size_t)F_ * GH_ * H_ * 2;       // 25,165,824
    short* Wx     = (short*)(ws + off); off += (size_t)F_ * 32 * 4 * 512 * 2;   //  1,572,864
    short* dW1_bf = (short*)(ws + off); off += (size_t)1024 * ZW_ * 2;          // 13,107,200
    short* dW2_bf = (short*)(ws + off); off += (size_t)1024 * 1024 * 2;         //  2,097,152
    float* sW1T   = (float*)(ws + off); off += (size_t)64 * 256 * 4;
    float* sW2T   = (float*)(ws + off); off += (size_t)256 * 256 * 4;
    float* sW3T   = (float*)(ws + off); off += (size_t)256 * 256 * 4;
    short* Z      = (short*)(ws + off); off += (size_t)B_ * ZW_ * 2;            // 52,428,800
    short* Z1     = (short*)(ws + off); off += (size_t)B_ * 1024 * 2;
    short* Z2     = (short*)(ws + off); off += (size_t)B_ * 1024 * 2;
    float* lsum   = (float*)(ws + off); off += 128 * 4;

    float* out = (float*)d_out;

    k_convert<<<2048, 256, 0, stream>>>(Whh, dW1, dW2, bih, bhh, Wih, sW1, sW2, sW3,
                                        Wpk, Wx, dW1_bf, dW2_bf, sW1T, sW2T, sW3T);
    k_lstm<<<768, 512, 0, stream>>>(Wpk, Wx, tfeat, tmask, h0, c0, Z);
    k_static<<<4096, 256, 0, stream>>>(sfeat, sW1T, sb1, sW2T, sb2, sW3T, sb3, Z);
    k_gemm_relu<<<dim3(32, 8), 256, 0, stream>>>(Z, dW1_bf, db1, Z1, B_, 1024, ZW_);
    k_gemm_relu<<<dim3(32, 8), 256, 0, stream>>>(Z1, dW2_bf, db2, Z2, B_, 1024, 1024);
    k_head3<<<128, 256, 0, stream>>>(Z2, dW3, db3, tgt, out, lsum);
    k_loss_final<<<1, 64, 0, stream>>>(lsum, out);
}

// Round 10
// 3953.609 us; speedup vs baseline: 7.9979x; 4.5175x over previous
//
#include <hip/hip_runtime.h>
#include <hip/hip_bf16.h>
#include <hip/hip_fp16.h>

#define B_ 4096
#define T_ 24
#define F_ 12
#define H_ 512
#define GH_ 2048   // 4*H
#define ZW_ 6400   // F*H + 256

// XOR swizzle (16B-fragment granularity, bijective within a 512-short row)
#define SWZ(row, elem) ((elem) ^ (((row) & 15) << 3))

typedef __attribute__((ext_vector_type(8))) short short8;
typedef __attribute__((ext_vector_type(4))) float f32x4;

__device__ __forceinline__ short f2bf(float f) {
    union { float f; unsigned int u; } v; v.f = f;
    unsigned int u = v.u;
    unsigned int r = (u + 0x7FFFu + ((u >> 16) & 1u)) >> 16;
    return (short)r;
}
__device__ __forceinline__ float bf2f(short b) {
    union { unsigned int u; float f; } v; v.u = ((unsigned int)(unsigned short)b) << 16;
    return v.f;
}
__device__ __forceinline__ float fastrcp(float x) { return __builtin_amdgcn_rcpf(x); }
__device__ __forceinline__ float sigm(float x) { return fastrcp(1.f + __expf(-x)); }
__device__ __forceinline__ float tanh_(float x) { return 1.f - 2.f * fastrcp(__expf(2.f * x) + 1.f); }

// ---------------------------------------------------------------- convert
// Whh packed to MFMA B-fragment order:
//   Wpk[(((f*32 + jb)*16 + kk)*4 + g)*512 + l*8 + e]
//     = bf16( Whh[f][g*512 + jb*16 + (l&15)][kk*32 + (l>>4)*8 + e] )
// Wx: x-part B-fragments (wx0, wx1, bias_hi, bias_lo, wx0, 0,0,0) on lq==0:
//   Wx[((f*32 + jb)*4 + g)*512 + l*8 + e]
__global__ void k_convert(const float* Whh, const float* dW1, const float* dW2,
                          const float* bih, const float* bhh, const float* Wih,
                          const float* sW1, const float* sW2, const float* sW3,
                          short* Wpk, short* Wx, short* odW1, short* odW2,
                          float* sW1T, float* sW2T, float* sW3T) {
    const int N2 = 1024 * ZW_;             // 6,553,600
    const int N3 = 1024 * 1024;
    const int N4 = F_ * 32 * 16 * 4 * 64;  // Wpk fragments of 8
    const int N5 = F_ * 32 * 4 * 64;       // Wx fragments of 8
    int idx = blockIdx.x * blockDim.x + threadIdx.x;
    int stride = gridDim.x * blockDim.x;
    for (int i = idx; i < N4; i += stride) {
        int l  = i & 63;
        int g  = (i >> 6) & 3;
        int kk = (i >> 8) & 15;
        int jb = (i >> 12) & 31;
        int f  = i >> 17;
        int row = g * 512 + jb * 16 + (l & 15);
        int col = kk * 32 + (l >> 4) * 8;
        const float* src = Whh + ((size_t)f * GH_ + row) * H_ + col;
        short tmp[8];
        #pragma unroll
        for (int e = 0; e < 8; e++) tmp[e] = f2bf(src[e]);
        *(short8*)(Wpk + (size_t)i * 8) = *(short8*)tmp;
    }
    for (int i = idx; i < N5; i += stride) {
        int l  = i & 63;
        int g  = (i >> 6) & 3;
        int jb = (i >> 8) & 31;
        int f  = i >> 13;
        short tmp[8] = {0, 0, 0, 0, 0, 0, 0, 0};
        if ((l >> 4) == 0) {
            int col = g * 512 + jb * 16 + (l & 15);
            float w0 = Wih[((size_t)f * GH_ + col) * 2];
            float w1 = Wih[((size_t)f * GH_ + col) * 2 + 1];
            float bs = bih[f * GH_ + col] + bhh[f * GH_ + col];
            short bh = f2bf(bs);
            short bl = f2bf(bs - bf2f(bh));
            short w0b = f2bf(w0);
            tmp[0] = w0b; tmp[1] = f2bf(w1); tmp[2] = bh; tmp[3] = bl; tmp[4] = w0b;
        }
        *(short8*)(Wx + (size_t)i * 8) = *(short8*)tmp;
    }
    for (int i = idx; i < N2; i += stride) odW1[i] = f2bf(dW1[i]);
    for (int i = idx; i < N3; i += stride) odW2[i] = f2bf(dW2[i]);
    for (int i = idx; i < 64 * 256; i += stride) {      // sW1T[i][t] = sW1[t][i]
        int r = i >> 8, t = i & 255;
        sW1T[i] = sW1[t * 64 + r];
    }
    for (int i = idx; i < 256 * 256; i += stride) {
        int r = i >> 8, t = i & 255;
        sW2T[i] = sW2[t * 256 + r];
        sW3T[i] = sW3[t * 256 + r];
    }
}

// ---------------------------------------------------------------- LSTM sub-step
// One j-subtile (16 cols) for one wave, 32-row tile (2 rowfrags).
// c lives in LDS f16 (thread-private cells, 2-way bank = free) -- removes all
// persistent per-thread register state. acc = 32 f32 only. kk loop unrolled
// by 2 ONLY: rounds 2-9 showed the fully-unrolled 16-kk loop's load-ahead
// window inflates live pressure ~40-60 regs past static counts -> spill.
template<int S>
__device__ __forceinline__ void lstm_step_sub(
    const short* hread, short* hwrite, _Float16* cbt,
    const short* Wb, const short* WxS,
    const float* xvp, const float* xmp,
    int l, int l15, int lq, int w)
{
    const short* Ws = Wb + ((size_t)S << 15) + l * 8;
    // x A-fragments (transient): rows r*16+l15, k-slots {xv_hi,xm,1,1,xv_lo}
    short8 ax[2];
    #pragma unroll
    for (int r = 0; r < 2; r++) {
        short8 v = {0, 0, 0, 0, 0, 0, 0, 0};
        if (lq == 0) {
            int row = r * 16 + l15;
            float xvf = xvp[row], xmf = xmp[row];
            short hi = f2bf(xvf);
            v[0] = hi; v[1] = f2bf(xmf);
            v[2] = (short)0x3F80; v[3] = (short)0x3F80;
            v[4] = f2bf(xvf - bf2f(hi));
        }
        ax[r] = v;
    }
    short8 bx[4];
    #pragma unroll
    for (int g = 0; g < 4; g++)
        bx[g] = *(const short8*)(WxS + S * 2048 + g * 512);
    const f32x4 zero = {0.f, 0.f, 0.f, 0.f};
    f32x4 acc[4][2];   // [gate][rowfrag] = 32 f32
    #pragma unroll
    for (int g = 0; g < 4; g++)
        #pragma unroll
        for (int r = 0; r < 2; r++)
            acc[g][r] = __builtin_amdgcn_mfma_f32_16x16x32_bf16(ax[r], bx[g], zero, 0, 0, 0);
    // K loop: 512 = 16 x 32; unroll 2 to cap the load window
    #pragma unroll 2
    for (int kk = 0; kk < 16; kk++) {
        int k = kk * 32 + lq * 8;
        short8 a[2], bfr[4];
        #pragma unroll
        for (int r = 0; r < 2; r++) {
            int row = r * 16 + l15;
            a[r] = *(const short8*)&hread[SWZ(row, row * 512 + k)];
        }
        #pragma unroll
        for (int g = 0; g < 4; g++)
            bfr[g] = *(const short8*)(Ws + (kk * 4 + g) * 512);
        #pragma unroll
        for (int g = 0; g < 4; g++)
            #pragma unroll
            for (int r = 0; r < 2; r++)
                acc[g][r] = __builtin_amdgcn_mfma_f32_16x16x32_bf16(a[r], bfr[g], acc[g][r], 0, 0, 0);
    }
    // cell update (c in LDS f16, thread-private) + h write
    int j = w * 64 + S * 16 + l15;
    #pragma unroll
    for (int r = 0; r < 2; r++)
        #pragma unroll
        for (int p = 0; p < 4; p++) {
            float iv = acc[0][r][p], fv = acc[1][r][p];
            float gv = acc[2][r][p], ov = acc[3][r][p];
            float cv = (float)cbt[(S * 8 + r * 4 + p) * 512];
            float cn = sigm(fv) * cv + sigm(iv) * tanh_(gv);
            cbt[(S * 8 + r * 4 + p) * 512] = (_Float16)cn;
            float hn = sigm(ov) * tanh_(cn);
            int row = r * 16 + lq * 4 + p;
            hwrite[SWZ(row, row * 512 + j)] = f2bf(hn);
        }
}

// grid 1536 (12 features x 128 batch-tiles of 32 rows), 512 threads (8 waves).
// h double-buffered bf16 in LDS (2x32KB, swizzled); c in LDS f16 (32KB);
// NO persistent per-thread register state -> spill impossible by construction.
// LDS ~98.5KB -> 1 block/CU, 8 waves. Weight stream 73.7GB from L2 is the
// structural floor (~2.25ms at 34.5 TB/s).
__global__ __launch_bounds__(512, 2)
void k_lstm(const short* __restrict__ Wpk,   // packed, see k_convert
            const short* __restrict__ Wx,    // x-part fragments
            const float* __restrict__ tfeat, // [B][T][F]
            const float* __restrict__ tmask,
            const float* __restrict__ h0,    // [F][B][H]
            const float* __restrict__ c0,
            short* __restrict__ Z)           // [B][6400] bf16
{
    __shared__ __align__(16) short hbuf[2][32 * 512];   // 2 x 32KB
    __shared__ _Float16 cbuf[32 * 512];                 // 32KB, [idx][tid]
    __shared__ float xv[2][32], xm[2][32];

    int bid = blockIdx.x;
    int wg = (bid & 7) * 192 + (bid >> 3);   // XCD swizzle (1536 = 8*192, bijective)
    int f = wg >> 7;
    int b0 = (wg & 127) * 32;
    int tid = threadIdx.x;
    int w = tid >> 6;
    int l = tid & 63;
    int l15 = l & 15, lq = l >> 4;

    // stage h0 -> hbuf[0] (bf16, swizzled): 32 rows x 512 cols
    {
        int row = tid >> 4, cg = (tid & 15) * 32;
        const float* src = h0 + ((size_t)f * B_ + b0 + row) * H_ + cg;
        #pragma unroll
        for (int i = 0; i < 32; i += 8) {
            short tmp[8];
            #pragma unroll
            for (int j = 0; j < 8; j++) tmp[j] = f2bf(src[i + j]);
            *(short8*)&hbuf[0][SWZ(row, row * 512 + cg + i)] = *(short8*)tmp;
        }
    }
    if (tid < 32)       xv[0][tid]      = tfeat[(size_t)(b0 + tid) * (T_ * F_) + f];
    else if (tid < 64)  xm[0][tid - 32] = tmask[(size_t)(b0 + tid - 32) * (T_ * F_) + f];

    // c0 -> cbuf f16: idx = s*8 + r*4 + p, thread-private column tid
    #pragma unroll
    for (int s = 0; s < 4; s++) {
        int j = w * 64 + s * 16 + l15;
        #pragma unroll
        for (int r = 0; r < 2; r++) {
            const float* cp = c0 + ((size_t)f * B_ + b0 + r * 16 + lq * 4) * H_ + j;
            #pragma unroll
            for (int p = 0; p < 4; p++)
                cbuf[(s * 8 + r * 4 + p) * 512 + tid] = (_Float16)cp[(size_t)p * H_];
        }
    }
    __syncthreads();

    const short* Wb  = Wpk + (((size_t)f * 32 + w * 4) << 15);
    const short* WxS = Wx + ((size_t)(f * 32 + w * 4) * 4) * 512 + l * 8;
    _Float16* cbt = cbuf + tid;

    #pragma unroll 1
    for (int t = 0; t < T_; t++) {
        int rb = t & 1, wb = rb ^ 1;
        // prefetch x(t+1) into the other buffer (ordered by end-of-step barrier)
        if (t < T_ - 1) {
            if (tid < 32)      xv[wb][tid]      = tfeat[(size_t)(b0 + tid) * (T_ * F_) + (t + 1) * F_ + f];
            else if (tid < 64) xm[wb][tid - 32] = tmask[(size_t)(b0 + tid - 32) * (T_ * F_) + (t + 1) * F_ + f];
        }
        const short* hr = hbuf[rb];
        short*       hw = hbuf[wb];
        const float* xvp = xv[rb];
        const float* xmp = xm[rb];
        lstm_step_sub<0>(hr, hw, cbt, Wb, WxS, xvp, xmp, l, l15, lq, w);
        lstm_step_sub<1>(hr, hw, cbt, Wb, WxS, xvp, xmp, l, l15, lq, w);
        lstm_step_sub<2>(hr, hw, cbt, Wb, WxS, xvp, xmp, l, l15, lq, w);
        lstm_step_sub<3>(hr, hw, cbt, Wb, WxS, xvp, xmp, l, l15, lq, w);
        __syncthreads();
    }

    // final h (in hbuf[0], T even) -> Z columns [f*512, f*512+512)
    {
        int row = tid >> 4, cg = (tid & 15) * 32;
        short* dst = Z + (size_t)(b0 + row) * ZW_ + f * H_ + cg;
        #pragma unroll
        for (int i = 0; i < 32; i += 8)
            *(short8*)(dst + i) = *(const short8*)&hbuf[0][SWZ(row, row * 512 + cg + i)];
    }
}

// ---------------------------------------------------------------- static MLP
__global__ void k_static(const float* __restrict__ X,
                         const float* __restrict__ sW1T, const float* __restrict__ sb1,
                         const float* __restrict__ sW2T, const float* __restrict__ sb2,
                         const float* __restrict__ sW3T, const float* __restrict__ sb3,
                         short* __restrict__ Z) {
    __shared__ float xs[64], s1[256], s2[256];
    int row = blockIdx.x, tid = threadIdx.x;
    if (tid < 64) xs[tid] = X[row * 64 + tid];
    __syncthreads();
    float a = sb1[tid];
    for (int i = 0; i < 64; i++) a += xs[i] * sW1T[i * 256 + tid];
    s1[tid] = fmaxf(a, 0.f);
    __syncthreads();
    a = sb2[tid];
    for (int i = 0; i < 256; i++) a += s1[i] * sW2T[i * 256 + tid];
    s2[tid] = fmaxf(a, 0.f);
    __syncthreads();
    a = sb3[tid];
    for (int i = 0; i < 256; i++) a += s2[i] * sW3T[i * 256 + tid];
    Z[(size_t)row * ZW_ + F_ * H_ + tid] = f2bf(fmaxf(a, 0.f));
}

// ---------------------------------------------------------------- GEMM + bias + relu
__global__ __launch_bounds__(256, 2)
void k_gemm_relu(const short* __restrict__ A, const short* __restrict__ W,
                 const float* __restrict__ bias, short* __restrict__ C,
                 int M, int N, int K) {
    __shared__ __align__(16) short at[128 * 128];
    int tid = threadIdx.x;
    int wid = tid >> 6, l = tid & 63, l15 = l & 15, lq = l >> 4;
    int wm = wid >> 1, wn = wid & 1;
    int mb = blockIdx.x * 128, nb = blockIdx.y * 128;
    f32x4 acc[4][4];   // [colfrag][rowfrag]
    #pragma unroll
    for (int n = 0; n < 4; n++)
        #pragma unroll
        for (int r = 0; r < 4; r++)
            acc[n][r] = (f32x4){0.f, 0.f, 0.f, 0.f};

    #pragma unroll 1
    for (int kc = 0; kc < K; kc += 128) {
        {   // stage A tile 128x128 bf16 (swizzled)
            int row = tid >> 1, off = (tid & 1) * 64;
            const short* src = A + (size_t)(mb + row) * K + kc + off;
            #pragma unroll
            for (int i = 0; i < 64; i += 8) {
                short8 v = *(const short8*)(src + i);
                int elem = (row * 128 + off + i) ^ ((row & 7) << 3);
                *(short8*)&at[elem] = v;
            }
        }
        __syncthreads();
        #pragma unroll
        for (int kk = 0; kk < 4; kk++) {
            int k = kk * 32 + lq * 8;
            short8 a[4], bfr[4];
            #pragma unroll
            for (int r = 0; r < 4; r++) {
                int row = wm * 64 + 16 * r + l15;
                int elem = (row * 128 + k) ^ ((row & 7) << 3);
                a[r] = *(const short8*)&at[elem];
            }
            #pragma unroll
            for (int n = 0; n < 4; n++)
                bfr[n] = *(const short8*)(W + (size_t)(nb + wn * 64 + 16 * n + l15) * K + kc + k);
            #pragma unroll
            for (int n = 0; n < 4; n++)
                #pragma unroll
                for (int r = 0; r < 4; r++)
                    acc[n][r] = __builtin_amdgcn_mfma_f32_16x16x32_bf16(a[r], bfr[n], acc[n][r], 0, 0, 0);
        }
        __syncthreads();
    }
    #pragma unroll
    for (int n = 0; n < 4; n++) {
        int col = nb + wn * 64 + 16 * n + l15;
        float bv = bias[col];
        #pragma unroll
        for (int r = 0; r < 4; r++)
            #pragma unroll
            for (int p = 0; p < 4; p++) {
                int row = mb + wm * 64 + 16 * r + lq * 4 + p;
                C[(size_t)row * N + col] = f2bf(fmaxf(acc[n][r][p] + bv, 0.f));
            }
    }
}

// ---------------------------------------------------------------- head layer 3 + BCE partials
__global__ void k_head3(const short* __restrict__ Z2, const float* __restrict__ W3,
                        const float* __restrict__ b3, const float* __restrict__ tgt,
                        float* __restrict__ out, float* __restrict__ lsum) {
    __shared__ float ls[32];
    int tid = threadIdx.x, wv = tid >> 6, l = tid & 63;
    int rsub = l >> 3, ks = l & 7;
    int row = blockIdx.x * 32 + wv * 8 + rsub;
    const short* z = Z2 + (size_t)row * 1024 + ks * 128;
    const float* w0 = W3 + ks * 128;
    const float* w1 = W3 + 1024 + ks * 128;
    float a0 = 0.f, a1 = 0.f;
    for (int i = 0; i < 128; i += 8) {
        short8 zv = *(const short8*)(z + i);
        #pragma unroll
        for (int j = 0; j < 8; j++) {
            float zf = bf2f(zv[j]);
            a0 += zf * w0[i + j];
            a1 += zf * w1[i + j];
        }
    }
    a0 += __shfl_xor(a0, 1); a0 += __shfl_xor(a0, 2); a0 += __shfl_xor(a0, 4);
    a1 += __shfl_xor(a1, 1); a1 += __shfl_xor(a1, 2); a1 += __shfl_xor(a1, 4);
    if (ks == 0) {
        float p0 = fmaxf(a0 + b3[0], 0.f), p1 = fmaxf(a1 + b3[1], 0.f);
        out[row * 2] = p0; out[row * 2 + 1] = p1;
        float t0 = tgt[row * 2], t1 = tgt[row * 2 + 1];
        ls[wv * 8 + rsub] = (p0 - p0 * t0 + __logf(1.f + __expf(-p0)))
                          + (p1 - p1 * t1 + __logf(1.f + __expf(-p1)));
    }
    __syncthreads();
    if (tid == 0) {
        float s = 0.f;
        for (int i = 0; i < 32; i++) s += ls[i];
        lsum[blockIdx.x] = s;
    }
}

__global__ void k_loss_final(const float* __restrict__ lsum, float* __restrict__ out) {
    int l = threadIdx.x;   // 64 threads
    float v = lsum[l] + lsum[l + 64];
    for (int m = 1; m < 64; m <<= 1) v += __shfl_xor(v, m);
    if (l == 0) out[B_ * 2] = v / (float)(B_ * 2);
}

// ---------------------------------------------------------------- launch
extern "C" void kernel_launch(void* const* d_in, const int* in_sizes, int n_in,
                              void* d_out, int out_size, void* d_ws, size_t ws_size,
                              hipStream_t stream) {
    const float* sfeat = (const float*)d_in[0];
    const float* tfeat = (const float*)d_in[1];
    const float* tmask = (const float*)d_in[2];
    const float* tgt   = (const float*)d_in[3];
    const float* h0    = (const float*)d_in[4];
    const float* c0    = (const float*)d_in[5];
    const float* Wih   = (const float*)d_in[6];
    const float* Whh   = (const float*)d_in[7];
    const float* bih   = (const float*)d_in[8];
    const float* bhh   = (const float*)d_in[9];
    const float* sW1   = (const float*)d_in[10];
    const float* sb1   = (const float*)d_in[11];
    const float* sW2   = (const float*)d_in[12];
    const float* sb2   = (const float*)d_in[13];
    const float* sW3   = (const float*)d_in[14];
    const float* sb3   = (const float*)d_in[15];
    const float* dW1   = (const float*)d_in[16];
    const float* db1   = (const float*)d_in[17];
    const float* dW2   = (const float*)d_in[18];
    const float* db2   = (const float*)d_in[19];
    const float* dW3   = (const float*)d_in[20];
    const float* db3   = (const float*)d_in[21];

    char* ws = (char*)d_ws;
    size_t off = 0;
    short* Wpk    = (short*)(ws + off); off += (size_t)F_ * GH_ * H_ * 2;       // 25,165,824
    short* Wx     = (short*)(ws + off); off += (size_t)F_ * 32 * 4 * 512 * 2;   //  1,572,864
    short* dW1_bf = (short*)(ws + off); off += (size_t)1024 * ZW_ * 2;          // 13,107,200
    short* dW2_bf = (short*)(ws + off); off += (size_t)1024 * 1024 * 2;         //  2,097,152
    float* sW1T   = (float*)(ws + off); off += (size_t)64 * 256 * 4;
    float* sW2T   = (float*)(ws + off); off += (size_t)256 * 256 * 4;
    float* sW3T   = (float*)(ws + off); off += (size_t)256 * 256 * 4;
    short* Z      = (short*)(ws + off); off += (size_t)B_ * ZW_ * 2;            // 52,428,800
    short* Z1     = (short*)(ws + off); off += (size_t)B_ * 1024 * 2;
    short* Z2     = (short*)(ws + off); off += (size_t)B_ * 1024 * 2;
    float* lsum   = (float*)(ws + off); off += 128 * 4;

    float* out = (float*)d_out;

    k_convert<<<2048, 256, 0, stream>>>(Whh, dW1, dW2, bih, bhh, Wih, sW1, sW2, sW3,
                                        Wpk, Wx, dW1_bf, dW2_bf, sW1T, sW2T, sW3T);
    k_lstm<<<1536, 512, 0, stream>>>(Wpk, Wx, tfeat, tmask, h0, c0, Z);
    k_static<<<4096, 256, 0, stream>>>(sfeat, sW1T, sb1, sW2T, sb2, sW3T, sb3, Z);
    k_gemm_relu<<<dim3(32, 8), 256, 0, stream>>>(Z, dW1_bf, db1, Z1, B_, 1024, ZW_);
    k_gemm_relu<<<dim3(32, 8), 256, 0, stream>>>(Z1, dW2_bf, db2, Z2, B_, 1024, 1024);
    k_head3<<<128, 256, 0, stream>>>(Z2, dW3, db3, tgt, out, lsum);
    k_loss_final<<<1, 64, 0, stream>>>(lsum, out);
}

// Round 12
// 3879.772 us; speedup vs baseline: 8.1501x; 1.0190x over previous
//
#include <hip/hip_runtime.h>
#include <hip/hip_bf16.h>
#include <hip/hip_fp16.h>

#define B_ 4096
#define T_ 24
#define F_ 12
#define H_ 512
#define GH_ 2048   // 4*H
#define ZW_ 6400   // F*H + 256
#define L2E 1.44269504088896340736f

// XOR swizzle (16B-fragment granularity, bijective within a 512-short row)
#define SWZ(row, elem) ((elem) ^ (((row) & 15) << 3))

typedef __attribute__((ext_vector_type(8))) short short8;
typedef __attribute__((ext_vector_type(4))) float f32x4;
typedef __attribute__((ext_vector_type(2))) __fp16 f16x2;   // matches cvt_pkrtz return

__device__ __forceinline__ short f2bf(float f) {
    union { float f; unsigned int u; } v; v.f = f;
    unsigned int u = v.u;
    unsigned int r = (u + 0x7FFFu + ((u >> 16) & 1u)) >> 16;
    return (short)r;
}
__device__ __forceinline__ float bf2f(short b) {
    union { unsigned int u; float f; } v; v.u = ((unsigned int)(unsigned short)b) << 16;
    return v.f;
}
__device__ __forceinline__ float fastrcp(float x) { return __builtin_amdgcn_rcpf(x); }
__device__ __forceinline__ float ex2(float x) { return __builtin_amdgcn_exp2f(x); }
// x pre-scaled by log2(e):   sigma(x_true) = rcp(1 + 2^-x)
__device__ __forceinline__ float sigm2(float x) { return fastrcp(1.f + ex2(-x)); }
// x pre-scaled by 2*log2(e): tanh(x_true) = 1 - 2*rcp(2^x + 1)
__device__ __forceinline__ float tanh2(float x) { return 1.f - 2.f * fastrcp(ex2(x) + 1.f); }

// ---------------------------------------------------------------- convert
// Whh packed to MFMA B-fragment order, PRE-SCALED by log2e (gate g=2: 2*log2e)
// so the epilogue uses native v_exp_f32 (2^x) with no per-cell rescale:
//   Wpk[(((f*32 + jb)*16 + kk)*4 + g)*512 + l*8 + e]
//     = bf16( sc[g] * Whh[f][g*512 + jb*16 + (l&15)][kk*32 + (l>>4)*8 + e] )
// Wx: x-part B-fragments (wx0, wx1, bias_hi, bias_lo, wx0, 0,0,0) on lq==0,
// same per-gate scaling.
__global__ void k_convert(const float* Whh, const float* dW1, const float* dW2,
                          const float* bih, const float* bhh, const float* Wih,
                          const float* sW1, const float* sW2, const float* sW3,
                          short* Wpk, short* Wx, short* odW1, short* odW2,
                          float* sW1T, float* sW2T, float* sW3T) {
    const int N2 = 1024 * ZW_;             // 6,553,600
    const int N3 = 1024 * 1024;
    const int N4 = F_ * 32 * 16 * 4 * 64;  // Wpk fragments of 8
    const int N5 = F_ * 32 * 4 * 64;       // Wx fragments of 8
    int idx = blockIdx.x * blockDim.x + threadIdx.x;
    int stride = gridDim.x * blockDim.x;
    for (int i = idx; i < N4; i += stride) {
        int l  = i & 63;
        int g  = (i >> 6) & 3;
        int kk = (i >> 8) & 15;
        int jb = (i >> 12) & 31;
        int f  = i >> 17;
        float sc = (g == 2) ? 2.f * L2E : L2E;
        int row = g * 512 + jb * 16 + (l & 15);
        int col = kk * 32 + (l >> 4) * 8;
        const float* src = Whh + ((size_t)f * GH_ + row) * H_ + col;
        short tmp[8];
        #pragma unroll
        for (int e = 0; e < 8; e++) tmp[e] = f2bf(src[e] * sc);
        *(short8*)(Wpk + (size_t)i * 8) = *(short8*)tmp;
    }
    for (int i = idx; i < N5; i += stride) {
        int l  = i & 63;
        int g  = (i >> 6) & 3;
        int jb = (i >> 8) & 31;
        int f  = i >> 13;
        short tmp[8] = {0, 0, 0, 0, 0, 0, 0, 0};
        if ((l >> 4) == 0) {
            float sc = (g == 2) ? 2.f * L2E : L2E;
            int col = g * 512 + jb * 16 + (l & 15);
            float w0 = Wih[((size_t)f * GH_ + col) * 2] * sc;
            float w1 = Wih[((size_t)f * GH_ + col) * 2 + 1] * sc;
            float bs = (bih[f * GH_ + col] + bhh[f * GH_ + col]) * sc;
            short bh = f2bf(bs);
            short bl = f2bf(bs - bf2f(bh));
            short w0b = f2bf(w0);
            tmp[0] = w0b; tmp[1] = f2bf(w1); tmp[2] = bh; tmp[3] = bl; tmp[4] = w0b;
        }
        *(short8*)(Wx + (size_t)i * 8) = *(short8*)tmp;
    }
    for (int i = idx; i < N2; i += stride) odW1[i] = f2bf(dW1[i]);
    for (int i = idx; i < N3; i += stride) odW2[i] = f2bf(dW2[i]);
    for (int i = idx; i < 64 * 256; i += stride) {      // sW1T[i][t] = sW1[t][i]
        int r = i >> 8, t = i & 255;
        sW1T[i] = sW1[t * 64 + r];
    }
    for (int i = idx; i < 256 * 256; i += stride) {
        int r = i >> 8, t = i & 255;
        sW2T[i] = sW2[t * 256 + r];
        sW3T[i] = sW3[t * 256 + r];
    }
}

// ---------------------------------------------------------------- LSTM sub-step
// One j-subtile (16 cols) for one wave, 32-row tile (2 rowfrags).
// c lives in 16 packed-f16 REGISTERS (f16x2 cpk[4][4], static idx) -- r10's
// c-in-LDS proved the structure spill-free; moving c to packed regs frees
// 32KB LDS (-> 2 blocks/CU) and kills 64 scalar LDS ops/thread/step.
// acc = 32 f32. kk loop unroll 2 ONLY (caps the load-ahead window; full
// unroll inflated live pressure 40-60 regs and spilled, rounds 2-9).
template<int S>
__device__ __forceinline__ void lstm_step_sub(
    const short* hread, short* hwrite, f16x2 (&cpk)[4][4],
    const short* Wb, const short* WxS,
    const float* xvp, const float* xmp,
    int l, int l15, int lq, int w)
{
    const short* Ws = Wb + ((size_t)S << 15) + l * 8;
    // x A-fragments (transient): rows r*16+l15, k-slots {xv_hi,xm,1,1,xv_lo}
    short8 ax[2];
    #pragma unroll
    for (int r = 0; r < 2; r++) {
        short8 v = {0, 0, 0, 0, 0, 0, 0, 0};
        if (lq == 0) {
            int row = r * 16 + l15;
            float xvf = xvp[row], xmf = xmp[row];
            short hi = f2bf(xvf);
            v[0] = hi; v[1] = f2bf(xmf);
            v[2] = (short)0x3F80; v[3] = (short)0x3F80;
            v[4] = f2bf(xvf - bf2f(hi));
        }
        ax[r] = v;
    }
    short8 bx[4];
    #pragma unroll
    for (int g = 0; g < 4; g++)
        bx[g] = *(const short8*)(WxS + S * 2048 + g * 512);
    const f32x4 zero = {0.f, 0.f, 0.f, 0.f};
    f32x4 acc[4][2];   // [gate][rowfrag] = 32 f32
    #pragma unroll
    for (int g = 0; g < 4; g++)
        #pragma unroll
        for (int r = 0; r < 2; r++)
            acc[g][r] = __builtin_amdgcn_mfma_f32_16x16x32_bf16(ax[r], bx[g], zero, 0, 0, 0);
    // K loop: 512 = 16 x 32; unroll 2 to cap the load window
    #pragma unroll 2
    for (int kk = 0; kk < 16; kk++) {
        int k = kk * 32 + lq * 8;
        short8 a[2], bfr[4];
        #pragma unroll
        for (int r = 0; r < 2; r++) {
            int row = r * 16 + l15;
            a[r] = *(const short8*)&hread[SWZ(row, row * 512 + k)];
        }
        #pragma unroll
        for (int g = 0; g < 4; g++)
            bfr[g] = *(const short8*)(Ws + (kk * 4 + g) * 512);
        #pragma unroll
        for (int g = 0; g < 4; g++)
            #pragma unroll
            for (int r = 0; r < 2; r++)
                acc[g][r] = __builtin_amdgcn_mfma_f32_16x16x32_bf16(a[r], bfr[g], acc[g][r], 0, 0, 0);
    }
    // cell update (c in packed-f16 regs) + h write via v_cvt_pk_bf16_f32
    int j = w * 64 + S * 16 + l15;
    #pragma unroll
    for (int r = 0; r < 2; r++) {
        #pragma unroll
        for (int pi = 0; pi < 2; pi++) {
            f16x2 cold = cpk[S][r * 2 + pi];
            float cn01[2], hn01[2];
            #pragma unroll
            for (int q = 0; q < 2; q++) {
                int p = pi * 2 + q;
                float iv = acc[0][r][p], fv = acc[1][r][p];
                float gv = acc[2][r][p], ov = acc[3][r][p];
                float cn = sigm2(fv) * (float)cold[q] + sigm2(iv) * tanh2(gv);
                cn01[q] = cn;
                hn01[q] = sigm2(ov) * tanh2(cn * (2.f * L2E));
            }
            cpk[S][r * 2 + pi] = __builtin_amdgcn_cvt_pkrtz(cn01[0], cn01[1]);
            unsigned hp;
            asm("v_cvt_pk_bf16_f32 %0, %1, %2" : "=v"(hp) : "v"(hn01[0]), "v"(hn01[1]));
            int row0 = r * 16 + lq * 4 + pi * 2;
            hwrite[SWZ(row0, row0 * 512 + j)]             = (short)(hp & 0xffffu);
            hwrite[SWZ(row0 + 1, (row0 + 1) * 512 + j)]   = (short)(hp >> 16);
        }
    }
}

// grid 1536 (12 features x 128 batch-tiles of 32 rows), 512 threads (8 waves).
// h double-buffered bf16 in LDS (2x32KB, swizzled); c in 16 packed-f16 regs;
// LDS ~67KB -> 2 blocks/CU = 4 waves/SIMD: co-resident blocks are not
// barrier-synced with each other, so their MFMA / VALU-epilogue / load phases
// interleave (r10 was serialization-bound at 1 block/CU: Mfma 28% + VALU 34%).
__global__ __launch_bounds__(512, 2)
void k_lstm(const short* __restrict__ Wpk,   // packed+prescaled, see k_convert
            const short* __restrict__ Wx,    // x-part fragments (prescaled)
            const float* __restrict__ tfeat, // [B][T][F]
            const float* __restrict__ tmask,
            const float* __restrict__ h0,    // [F][B][H]
            const float* __restrict__ c0,
            short* __restrict__ Z)           // [B][6400] bf16
{
    __shared__ __align__(16) short hbuf[2][32 * 512];   // 2 x 32KB
    __shared__ float xv[2][32], xm[2][32];

    int bid = blockIdx.x;
    int wg = (bid & 7) * 192 + (bid >> 3);   // XCD swizzle (1536 = 8*192, bijective)
    int f = wg >> 7;
    int b0 = (wg & 127) * 32;
    int tid = threadIdx.x;
    int w = tid >> 6;
    int l = tid & 63;
    int l15 = l & 15, lq = l >> 4;

    // stage h0 -> hbuf[0] (bf16, swizzled): 32 rows x 512 cols
    {
        int row = tid >> 4, cg = (tid & 15) * 32;
        const float* src = h0 + ((size_t)f * B_ + b0 + row) * H_ + cg;
        #pragma unroll
        for (int i = 0; i < 32; i += 8) {
            short tmp[8];
            #pragma unroll
            for (int j = 0; j < 8; j++) tmp[j] = f2bf(src[i + j]);
            *(short8*)&hbuf[0][SWZ(row, row * 512 + cg + i)] = *(short8*)tmp;
        }
    }
    if (tid < 32)       xv[0][tid]      = tfeat[(size_t)(b0 + tid) * (T_ * F_) + f];
    else if (tid < 64)  xm[0][tid - 32] = tmask[(size_t)(b0 + tid - 32) * (T_ * F_) + f];

    // c0 -> packed f16 regs: cpk[s][r*2+pi] holds cells p=2pi, 2pi+1
    f16x2 cpk[4][4];
    #pragma unroll
    for (int s = 0; s < 4; s++) {
        int j = w * 64 + s * 16 + l15;
        #pragma unroll
        for (int r = 0; r < 2; r++) {
            const float* cp = c0 + ((size_t)f * B_ + b0 + r * 16 + lq * 4) * H_ + j;
            #pragma unroll
            for (int pi = 0; pi < 2; pi++)
                cpk[s][r * 2 + pi] = __builtin_amdgcn_cvt_pkrtz(
                    cp[(size_t)(pi * 2) * H_], cp[(size_t)(pi * 2 + 1) * H_]);
        }
    }
    __syncthreads();

    const short* Wb  = Wpk + (((size_t)f * 32 + w * 4) << 15);
    const short* WxS = Wx + ((size_t)(f * 32 + w * 4) * 4) * 512 + l * 8;

    #pragma unroll 1
    for (int t = 0; t < T_; t++) {
        int rb = t & 1, wb = rb ^ 1;
        // prefetch x(t+1) into the other buffer (ordered by end-of-step barrier)
        if (t < T_ - 1) {
            if (tid < 32)      xv[wb][tid]      = tfeat[(size_t)(b0 + tid) * (T_ * F_) + (t + 1) * F_ + f];
            else if (tid < 64) xm[wb][tid - 32] = tmask[(size_t)(b0 + tid - 32) * (T_ * F_) + (t + 1) * F_ + f];
        }
        const short* hr = hbuf[rb];
        short*       hw = hbuf[wb];
        const float* xvp = xv[rb];
        const float* xmp = xm[rb];
        lstm_step_sub<0>(hr, hw, cpk, Wb, WxS, xvp, xmp, l, l15, lq, w);
        lstm_step_sub<1>(hr, hw, cpk, Wb, WxS, xvp, xmp, l, l15, lq, w);
        lstm_step_sub<2>(hr, hw, cpk, Wb, WxS, xvp, xmp, l, l15, lq, w);
        lstm_step_sub<3>(hr, hw, cpk, Wb, WxS, xvp, xmp, l, l15, lq, w);
        __syncthreads();
    }

    // final h (in hbuf[0], T even) -> Z columns [f*512, f*512+512)
    {
        int row = tid >> 4, cg = (tid & 15) * 32;
        short* dst = Z + (size_t)(b0 + row) * ZW_ + f * H_ + cg;
        #pragma unroll
        for (int i = 0; i < 32; i += 8)
            *(short8*)(dst + i) = *(const short8*)&hbuf[0][SWZ(row, row * 512 + cg + i)];
    }
}

// ---------------------------------------------------------------- static MLP
__global__ void k_static(const float* __restrict__ X,
                         const float* __restrict__ sW1T, const float* __restrict__ sb1,
                         const float* __restrict__ sW2T, const float* __restrict__ sb2,
                         const float* __restrict__ sW3T, const float* __restrict__ sb3,
                         short* __restrict__ Z) {
    __shared__ float xs[64], s1[256], s2[256];
    int row = blockIdx.x, tid = threadIdx.x;
    if (tid < 64) xs[tid] = X[row * 64 + tid];
    __syncthreads();
    float a = sb1[tid];
    for (int i = 0; i < 64; i++) a += xs[i] * sW1T[i * 256 + tid];
    s1[tid] = fmaxf(a, 0.f);
    __syncthreads();
    a = sb2[tid];
    for (int i = 0; i < 256; i++) a += s1[i] * sW2T[i * 256 + tid];
    s2[tid] = fmaxf(a, 0.f);
    __syncthreads();
    a = sb3[tid];
    for (int i = 0; i < 256; i++) a += s2[i] * sW3T[i * 256 + tid];
    Z[(size_t)row * ZW_ + F_ * H_ + tid] = f2bf(fmaxf(a, 0.f));
}

// ---------------------------------------------------------------- GEMM + bias + relu
__global__ __launch_bounds__(256, 2)
void k_gemm_relu(const short* __restrict__ A, const short* __restrict__ W,
                 const float* __restrict__ bias, short* __restrict__ C,
                 int M, int N, int K) {
    __shared__ __align__(16) short at[128 * 128];
    int tid = threadIdx.x;
    int wid = tid >> 6, l = tid & 63, l15 = l & 15, lq = l >> 4;
    int wm = wid >> 1, wn = wid & 1;
    int mb = blockIdx.x * 128, nb = blockIdx.y * 128;
    f32x4 acc[4][4];   // [colfrag][rowfrag]
    #pragma unroll
    for (int n = 0; n < 4; n++)
        #pragma unroll
        for (int r = 0; r < 4; r++)
            acc[n][r] = (f32x4){0.f, 0.f, 0.f, 0.f};

    #pragma unroll 1
    for (int kc = 0; kc < K; kc += 128) {
        {   // stage A tile 128x128 bf16 (swizzled)
            int row = tid >> 1, off = (tid & 1) * 64;
            const short* src = A + (size_t)(mb + row) * K + kc + off;
            #pragma unroll
            for (int i = 0; i < 64; i += 8) {
                short8 v = *(const short8*)(src + i);
                int elem = (row * 128 + off + i) ^ ((row & 7) << 3);
                *(short8*)&at[elem] = v;
            }
        }
        __syncthreads();
        #pragma unroll
        for (int kk = 0; kk < 4; kk++) {
            int k = kk * 32 + lq * 8;
            short8 a[4], bfr[4];
            #pragma unroll
            for (int r = 0; r < 4; r++) {
                int row = wm * 64 + 16 * r + l15;
                int elem = (row * 128 + k) ^ ((row & 7) << 3);
                a[r] = *(const short8*)&at[elem];
            }
            #pragma unroll
            for (int n = 0; n < 4; n++)
                bfr[n] = *(const short8*)(W + (size_t)(nb + wn * 64 + 16 * n + l15) * K + kc + k);
            #pragma unroll
            for (int n = 0; n < 4; n++)
                #pragma unroll
                for (int r = 0; r < 4; r++)
                    acc[n][r] = __builtin_amdgcn_mfma_f32_16x16x32_bf16(a[r], bfr[n], acc[n][r], 0, 0, 0);
        }
        __syncthreads();
    }
    #pragma unroll
    for (int n = 0; n < 4; n++) {
        int col = nb + wn * 64 + 16 * n + l15;
        float bv = bias[col];
        #pragma unroll
        for (int r = 0; r < 4; r++)
            #pragma unroll
            for (int p = 0; p < 4; p++) {
                int row = mb + wm * 64 + 16 * r + lq * 4 + p;
                C[(size_t)row * N + col] = f2bf(fmaxf(acc[n][r][p] + bv, 0.f));
            }
    }
}

// ---------------------------------------------------------------- head layer 3 + BCE partials
__global__ void k_head3(const short* __restrict__ Z2, const float* __restrict__ W3,
                        const float* __restrict__ b3, const float* __restrict__ tgt,
                        float* __restrict__ out, float* __restrict__ lsum) {
    __shared__ float ls[32];
    int tid = threadIdx.x, wv = tid >> 6, l = tid & 63;
    int rsub = l >> 3, ks = l & 7;
    int row = blockIdx.x * 32 + wv * 8 + rsub;
    const short* z = Z2 + (size_t)row * 1024 + ks * 128;
    const float* w0 = W3 + ks * 128;
    const float* w1 = W3 + 1024 + ks * 128;
    float a0 = 0.f, a1 = 0.f;
    for (int i = 0; i < 128; i += 8) {
        short8 zv = *(const short8*)(z + i);
        #pragma unroll
        for (int j = 0; j < 8; j++) {
            float zf = bf2f(zv[j]);
            a0 += zf * w0[i + j];
            a1 += zf * w1[i + j];
        }
    }
    a0 += __shfl_xor(a0, 1); a0 += __shfl_xor(a0, 2); a0 += __shfl_xor(a0, 4);
    a1 += __shfl_xor(a1, 1); a1 += __shfl_xor(a1, 2); a1 += __shfl_xor(a1, 4);
    if (ks == 0) {
        float p0 = fmaxf(a0 + b3[0], 0.f), p1 = fmaxf(a1 + b3[1], 0.f);
        out[row * 2] = p0; out[row * 2 + 1] = p1;
        float t0 = tgt[row * 2], t1 = tgt[row * 2 + 1];
        ls[wv * 8 + rsub] = (p0 - p0 * t0 + __logf(1.f + __expf(-p0)))
                          + (p1 - p1 * t1 + __logf(1.f + __expf(-p1)));
    }
    __syncthreads();
    if (tid == 0) {
        float s = 0.f;
        for (int i = 0; i < 32; i++) s += ls[i];
        lsum[blockIdx.x] = s;
    }
}

__global__ void k_loss_final(const float* __restrict__ lsum, float* __restrict__ out) {
    int l = threadIdx.x;   // 64 threads
    float v = lsum[l] + lsum[l + 64];
    for (int m = 1; m < 64; m <<= 1) v += __shfl_xor(v, m);
    if (l == 0) out[B_ * 2] = v / (float)(B_ * 2);
}

// ---------------------------------------------------------------- launch
extern "C" void kernel_launch(void* const* d_in, const int* in_sizes, int n_in,
                              void* d_out, int out_size, void* d_ws, size_t ws_size,
                              hipStream_t stream) {
    const float* sfeat = (const float*)d_in[0];
    const float* tfeat = (const float*)d_in[1];
    const float* tmask = (const float*)d_in[2];
    const float* tgt   = (const float*)d_in[3];
    const float* h0    = (const float*)d_in[4];
    const float* c0    = (const float*)d_in[5];
    const float* Wih   = (const float*)d_in[6];
    const float* Whh   = (const float*)d_in[7];
    const float* bih   = (const float*)d_in[8];
    const float* bhh   = (const float*)d_in[9];
    const float* sW1   = (const float*)d_in[10];
    const float* sb1   = (const float*)d_in[11];
    const float* sW2   = (const float*)d_in[12];
    const float* sb2   = (const float*)d_in[13];
    const float* sW3   = (const float*)d_in[14];
    const float* sb3   = (const float*)d_in[15];
    const float* dW1   = (const float*)d_in[16];
    const float* db1   = (const float*)d_in[17];
    const float* dW2   = (const float*)d_in[18];
    const float* db2   = (const float*)d_in[19];
    const float* dW3   = (const float*)d_in[20];
    const float* db3   = (const float*)d_in[21];

    char* ws = (char*)d_ws;
    size_t off = 0;
    short* Wpk    = (short*)(ws + off); off += (size_t)F_ * GH_ * H_ * 2;       // 25,165,824
    short* Wx     = (short*)(ws + off); off += (size_t)F_ * 32 * 4 * 512 * 2;   //  1,572,864
    short* dW1_bf = (short*)(ws + off); off += (size_t)1024 * ZW_ * 2;          // 13,107,200
    short* dW2_bf = (short*)(ws + off); off += (size_t)1024 * 1024 * 2;         //  2,097,152
    float* sW1T   = (float*)(ws + off); off += (size_t)64 * 256 * 4;
    float* sW2T   = (float*)(ws + off); off += (size_t)256 * 256 * 4;
    float* sW3T   = (float*)(ws + off); off += (size_t)256 * 256 * 4;
    short* Z      = (short*)(ws + off); off += (size_t)B_ * ZW_ * 2;            // 52,428,800
    short* Z1     = (short*)(ws + off); off += (size_t)B_ * 1024 * 2;
    short* Z2     = (short*)(ws + off); off += (size_t)B_ * 1024 * 2;
    float* lsum   = (float*)(ws + off); off += 128 * 4;

    float* out = (float*)d_out;

    k_convert<<<2048, 256, 0, stream>>>(Whh, dW1, dW2, bih, bhh, Wih, sW1, sW2, sW3,
                                        Wpk, Wx, dW1_bf, dW2_bf, sW1T, sW2T, sW3T);
    k_lstm<<<1536, 512, 0, stream>>>(Wpk, Wx, tfeat, tmask, h0, c0, Z);
    k_static<<<4096, 256, 0, stream>>>(sfeat, sW1T, sb1, sW2T, sb2, sW3T, sb3, Z);
    k_gemm_relu<<<dim3(32, 8), 256, 0, stream>>>(Z, dW1_bf, db1, Z1, B_, 1024, ZW_);
    k_gemm_relu<<<dim3(32, 8), 256, 0, stream>>>(Z1, dW2_bf, db2, Z2, B_, 1024, 1024);
    k_head3<<<128, 256, 0, stream>>>(Z2, dW3, db3, tgt, out, lsum);
    k_loss_final<<<1, 64, 0, stream>>>(lsum, out);
}